// Round 9
// baseline (803.316 us; speedup 1.0000x reference)
//
#include <hip/hip_runtime.h>
#include <hip/hip_bf16.h>
#include <stdint.h>

// Performer (FAVOR+) forward, MI355X/gfx950.
// B=4, N=4096, E=1024, H=16, D=64, M(features)=256.
// bf16 MFMA (16x16x32) everywhere matmul-shaped, fp32 accumulate/epilogues.
// kf never materialized: kf = ratio*(e^-stab * U + eps), U = exp(dd-diag) is
// stab-free; context/k_sum assembled linearly from fused U^T·v and U^T·1.
// R3: k_fk_ctx barrier-free (per-wave sU, direct global frags, vT scratch).
// R4: k_fq_attn operand-swapped feature GEMM; XCD swizzle on k_gemm.
// R5: k_fk_ctx per-token-granule accR strip. MEASURED: 85.5 -> 74 us.
// R6: k_fq_attn spill fix (accC strip). MEASURED: total 578 -> 563 us.
// R7 FAILED: (256,3) cap squeezed allocator -> spill (WRITE 119MB), 133 us.
// R8 FAILED: 8-wave/32-feature split + (512,4) -> 64-reg budget -> spill
// (WRITE 169MB), 166 us. LESSON (m69): occupancy buckets are 64/128/256
// unified regs; fk_ctx demand ~150-176 is locked in the (128,256] bucket ->
// 2 waves/SIMD regardless. Stop squeezing; use the ~80 regs of FREE headroom.
// R9: revert fk_ctx to R6 form + af (kb-fragment) ping-pong prefetch across
// s-iterations (+16 regs, ~192 <= 256, same bucket): next sub-tile's 16
// global loads fly under current sub-tile's MFMA+epilogue. Pure ILP.

#define TOKN  16384
#define SEQ   4096
#define EMB   1024
#define NHEAD 16
#define HD    64
#define NF    256
#define BHN   64   // batch*heads

static __device__ __forceinline__ constexpr float c1f()  { return 0.35355339059327379f; } // 64^-0.25
static __device__ __forceinline__ constexpr float ratf() { return 0.0625f; }              // 256^-0.5
static __device__ __forceinline__ constexpr float kepsf(){ return 1e-4f; }

typedef unsigned short u16;
typedef unsigned int   u32;
typedef __attribute__((ext_vector_type(8))) short bf16x8;
typedef __attribute__((ext_vector_type(4))) float f32x4;
typedef __attribute__((ext_vector_type(4))) u16   u16x4;

union U8 { bf16x8 v8; u16x4 q[2]; };

__device__ __forceinline__ float bf2f(u16 u) { return __uint_as_float(((u32)u) << 16); }
__device__ __forceinline__ u16 f2bf(float f) {
  u32 u = __float_as_uint(f);
  u += 0x7fffu + ((u >> 16) & 1u);   // RNE
  return (u16)(u >> 16);
}
// order-preserving float<->uint encoding for atomicMax on a float
__device__ __forceinline__ u32 encf(float f) {
  u32 u = __float_as_uint(f);
  return (u & 0x80000000u) ? ~u : (u | 0x80000000u);
}
__device__ __forceinline__ float decf(u32 e) {
  u32 u = (e & 0x80000000u) ? (e & 0x7fffffffu) : ~e;
  return __uint_as_float(u);
}

__device__ __forceinline__ void gl2lds16(const u16* g, void* l) {
  __builtin_amdgcn_global_load_lds(
      (const __attribute__((address_space(1))) u32*)g,
      (__attribute__((address_space(3))) u32*)l, 16, 0, 0);
}

#define ZERO_ACC(acc)                         \
  _Pragma("unroll") for (int _i = 0; _i < 4; _i++) \
  _Pragma("unroll") for (int _j = 0; _j < 4; _j++) acc[_i][_j] = (f32x4)0.0f;

// ---------------------------------------------------------------------------
// m97-style MFMA GEMM core: C[m][n] += sum_k A[m][k]*B[n][k] (both row-major,
// K contiguous). 256 thr = 4 waves; wave tile 64x64 (4x4 of 16x16x32). BK=32.
// ---------------------------------------------------------------------------
template <int BM, int BN>
__device__ __forceinline__ void gemm_core(const u16* __restrict__ Ag, long lda,
                                          const u16* __restrict__ Bg, long ldb,
                                          int K, u16* sA, u16* sB,
                                          f32x4 (&acc)[4][4]) {
  const int tid = threadIdx.x;
  const int w = tid >> 6, l = tid & 63;
  constexpr int WM = BM / 64;
  const int wm = w % WM, wn = w / WM;
  const int lrow = l & 15, lk = (l >> 4) * 8;
  constexpr int AI = (BM * 4) / 256;
  constexpr int BI = (BN * 4) / 256;

  for (int k0 = 0; k0 < K; k0 += 32) {
    __syncthreads();
#pragma unroll
    for (int i = 0; i < AI; i++) {
      int q = i * 256 + tid;
      gl2lds16(Ag + (long)(q >> 2) * lda + k0 + (q & 3) * 8,
               (char*)sA + i * 4096 + w * 1024);
    }
#pragma unroll
    for (int i = 0; i < BI; i++) {
      int q = i * 256 + tid;
      gl2lds16(Bg + (long)(q >> 2) * ldb + k0 + (q & 3) * 8,
               (char*)sB + i * 4096 + w * 1024);
    }
    __syncthreads();
    bf16x8 af[4], bfr[4];
#pragma unroll
    for (int mt = 0; mt < 4; mt++)
      af[mt] = *(const bf16x8*)(sA + ((wm * 64 + mt * 16 + lrow) * 32 + lk));
#pragma unroll
    for (int nt = 0; nt < 4; nt++)
      bfr[nt] = *(const bf16x8*)(sB + ((wn * 64 + nt * 16 + lrow) * 32 + lk));
#pragma unroll
    for (int mt = 0; mt < 4; mt++)
#pragma unroll
      for (int nt = 0; nt < 4; nt++)
        acc[mt][nt] = __builtin_amdgcn_mfma_f32_16x16x32_bf16(af[mt], bfr[nt], acc[mt][nt], 0, 0, 0);
  }
}

// ---------------------------------------------------------------------------
// Big 128x128 GEMM: C = A*B^T + bias. XCD-aware block swizzle: consecutive
// groups of nwg/8 tiles land on one XCD so an A-panel's 8 column-tiles share
// that XCD's private L2 (A slice/XCD = 4MB = L2 size) instead of streaming
// the full 32MB A through every XCD L2.
// ---------------------------------------------------------------------------
template <bool BF16OUT>
__global__ __launch_bounds__(256) void k_gemm(const u16* __restrict__ A, const u16* __restrict__ Bw,
                                              void* __restrict__ Cout, const float* __restrict__ bias,
                                              int K, int lda, int ldb, int ldc) {
  __shared__ __align__(16) u16 sA[128 * 32];
  __shared__ __align__(16) u16 sB[128 * 32];
  const int nbx = gridDim.x;
  const int nwg = nbx * gridDim.y;
  int lin = blockIdx.y * nbx + blockIdx.x;
  if ((nwg & 7) == 0) {                    // bijective XCD swizzle (nwg%8==0)
    int per = nwg >> 3;
    lin = (lin & 7) * per + (lin >> 3);
  }
  const int m0 = (lin / nbx) * 128, n0 = (lin % nbx) * 128;
  f32x4 acc[4][4]; ZERO_ACC(acc);
  gemm_core<128, 128>(A + (long)m0 * lda, lda, Bw + (long)n0 * ldb, ldb, K, sA, sB, acc);
  const int l = threadIdx.x & 63, w = threadIdx.x >> 6;
  const int wm = w & 1, wn = w >> 1, lr4 = (l >> 4) * 4, lc = l & 15;
#pragma unroll
  for (int nt = 0; nt < 4; nt++) {
    int gcol = n0 + wn * 64 + nt * 16 + lc;
    float bia = bias[gcol];
#pragma unroll
    for (int mt = 0; mt < 4; mt++)
#pragma unroll
      for (int r = 0; r < 4; r++) {
        int grow = m0 + wm * 64 + mt * 16 + lr4 + r;
        float v = acc[mt][nt][r] + bia;
        if (BF16OUT) ((u16*)Cout)[(long)grow * ldc + gcol] = f2bf(v);
        else         ((float*)Cout)[(long)grow * ldc + gcol] = v;
      }
  }
}

// ---------------------------------------------------------------------------
// v transpose: vb [B,N,E] head-sliced -> vT[bh][d][n] (bf16), plus vsum[bh][d].
// ---------------------------------------------------------------------------
__global__ __launch_bounds__(256) void k_vT(const u16* __restrict__ vb, u16* __restrict__ vT,
                                            float* __restrict__ vsum) {
  __shared__ u16 t[64][72];   // 72 stride: 8B-aligned rows, conflict-benign
  const int bh = blockIdx.y, n0 = blockIdx.x * 64, b = bh >> 4, h = bh & 15;
  const int tid = threadIdx.x;
#pragma unroll
  for (int i = 0; i < 2; i++) {
    int idx = i * 256 + tid, row = idx >> 3, c8 = idx & 7;
    U8 u;
    u.v8 = *(const bf16x8*)&vb[((long)(b * SEQ) + n0 + row) * EMB + h * HD + c8 * 8];
    *(u16x4*)&t[row][c8 * 8]     = u.q[0];
    *(u16x4*)&t[row][c8 * 8 + 4] = u.q[1];
  }
  __syncthreads();
  const int nq = tid & 15, dh = tid >> 4;
#pragma unroll
  for (int i = 0; i < 4; i++) {
    int d = i * 16 + dh;
    u16x4 pk; float s = 0.f;
#pragma unroll
    for (int j = 0; j < 4; j++) { u16 v = t[nq * 4 + j][d]; pk[j] = v; s += bf2f(v); }
    *(u16x4*)&vT[((long)bh * HD + d) * SEQ + n0 + nq * 4] = pk;
    s += __shfl_xor(s, 1); s += __shfl_xor(s, 2);
    s += __shfl_xor(s, 4); s += __shfl_xor(s, 8);
    if (nq == 0) atomicAdd(&vsum[bh * HD + d], s);
  }
}

// ---------------------------------------------------------------------------
// Fused key features + context partials, BARRIER-FREE.
// Grid (16 chunks, 64 bh); block = 256 thr = 4 waves; 256 tokens in 4
// sub-tiles of 64. Each wave owns 64 features. A-frags (k) and B-frags (vT)
// direct from global; U transposed through a per-wave 8KB LDS region
// (intra-wave only -> no __syncthreads at all).
// part[z=bh*16+ck][m=256][d=64] bf16. su/stab via atomics.
// R5: feature GEMM per-token-granule (accR[4] recycled) -> one persistent
// 64-reg accumulator (acc2). 2 waves/SIMD (176 regs, (128,256] bucket).
// R9: af ping-pong prefetch across s (afA/afB, +16 regs, same bucket):
// sub-tile s+1's 16 kb loads issue before sub-tile s's compute.
// ---------------------------------------------------------------------------
__global__ __launch_bounds__(256, 2) void k_fk_ctx(const u16* __restrict__ kb, const u16* __restrict__ vT,
                                                   const u16* __restrict__ projb, u16* __restrict__ part,
                                                   float* __restrict__ su, u32* __restrict__ stabEnc) {
  __shared__ __align__(16) u16 sU[4][64 * 64];   // per-wave 8KB regions
  const int ck = blockIdx.x, bh = blockIdx.y, b = bh >> 4, h = bh & 15;
  const int tid = threadIdx.x, w = tid >> 6, l = tid & 63;
  const int c = l & 15, g = l >> 4;
  u16* sUw = &sU[w][0];
  const int sw = c & 7;

  // proj B-fragments in registers: features w*64+nt*16+c, k = k0*32+g*8+j
  bf16x8 pf[4][2];
#pragma unroll
  for (int nt = 0; nt < 4; nt++)
#pragma unroll
    for (int k0 = 0; k0 < 2; k0++)
      pf[nt][k0] = *(const bf16x8*)&projb[(w * 64 + nt * 16 + c) * 64 + k0 * 32 + g * 8];

  f32x4 acc2[4][4]; ZERO_ACC(acc2);   // ctx: rows=features(wave-local), cols=d
  float suv[4] = {0.f, 0.f, 0.f, 0.f};
  float amax = -1e30f;                // max raw acc; stab = c1*amax (monotone)
  const long tok0 = (long)b * SEQ + ck * 256;

  // R9: af double-buffer. Load sub-tile 0 up front; inside the (unrolled)
  // s-loop, issue s+1's loads before s's compute so HBM/L2 latency hides
  // under ~900 cycles of MFMA+epilogue. Static buffer selection via unroll.
  bf16x8 afA[4][2], afB[4][2];
#pragma unroll
  for (int mt = 0; mt < 4; mt++)
#pragma unroll
    for (int k0 = 0; k0 < 2; k0++)
      afA[mt][k0] = *(const bf16x8*)&kb[(tok0 + mt * 16 + c) * EMB + h * HD + k0 * 32 + g * 8];

#pragma unroll
  for (int s = 0; s < 4; s++) {
    bf16x8 (&af)[4][2]  = (s & 1) ? afB : afA;
    bf16x8 (&afN)[4][2] = (s & 1) ? afA : afB;
    if (s < 3) {
      const long tn = tok0 + (s + 1) * 64;
#pragma unroll
      for (int mt = 0; mt < 4; mt++)
#pragma unroll
        for (int k0 = 0; k0 < 2; k0++)
          afN[mt][k0] = *(const bf16x8*)&kb[(tn + mt * 16 + c) * EMB + h * HD + k0 * 32 + g * 8];
    }
    // hoist vT B-frags for the ctx GEMM: latency hides under GEMM + epilogue
    bf16x8 vf[2][4];
#pragma unroll
    for (int k0 = 0; k0 < 2; k0++)
#pragma unroll
      for (int nt = 0; nt < 4; nt++)
        vf[k0][nt] = *(const bf16x8*)&vT[((long)bh * HD + nt * 16 + c) * SEQ +
                                         ck * 256 + s * 64 + k0 * 32 + g * 8];

    // per-token-granule mt: diag + one 16-row strip of the feature GEMM +
    // epilogue, with accR recycled (peak acc pressure 64+16 not 64+64).
#pragma unroll
    for (int mt = 0; mt < 4; mt++) {
      float ss = 0.f;
#pragma unroll
      for (int k0 = 0; k0 < 2; k0++)
#pragma unroll
        for (int j = 0; j < 8; j++) {
          float v = bf2f((u16)af[mt][k0][j]);
          ss += v * v;
        }
      ss += __shfl_xor(ss, 16);
      ss += __shfl_xor(ss, 32);
      const float dgrow = ss * 0.0625f;   // diag of token mt*16+c
      f32x4 accR[4];
#pragma unroll
      for (int nt = 0; nt < 4; nt++) accR[nt] = (f32x4)0.0f;
#pragma unroll
      for (int k0 = 0; k0 < 2; k0++)
#pragma unroll
        for (int nt = 0; nt < 4; nt++)
          accR[nt] = __builtin_amdgcn_mfma_f32_16x16x32_bf16(af[mt][k0], pf[nt][k0], accR[nt], 0, 0, 0);
      // epilogue: U = exp(c1*acc - diag) -> per-wave sU (swizzled), su, stab
      float dg[4];
#pragma unroll
      for (int r = 0; r < 4; r++) dg[r] = __shfl(dgrow, g * 4 + r);
#pragma unroll
      for (int nt = 0; nt < 4; nt++) {
        u16x4 pk;
#pragma unroll
        for (int r = 0; r < 4; r++) {
          float a = accR[nt][r];
          amax = fmaxf(amax, a);
          float U = __expf(fmaf(a, c1f(), -dg[r]));
          pk[r] = f2bf(U);
          suv[nt] += U;
        }
        // write tokens granule G=mt*4+g (pair P=mt*2+(g>>1), b=g&1), row nt*16+c
        *(u16x4*)&sUw[(nt * 16 + c) * 64 + (((mt * 2 + (g >> 1)) ^ sw) * 2 + (g & 1)) * 4] = pk;
      }
    }
    // ctx GEMM: acc2[m][d] += sum_n U^T[m][n] * vT[d][n]  (intra-wave sU reads)
#pragma unroll
    for (int k0 = 0; k0 < 2; k0++) {
      bf16x8 uf[4];
#pragma unroll
      for (int mt = 0; mt < 4; mt++)
        uf[mt] = *(const bf16x8*)&sUw[(mt * 16 + c) * 64 + ((k0 * 4 + g) ^ sw) * 8];
#pragma unroll
      for (int mt = 0; mt < 4; mt++)
#pragma unroll
        for (int nt = 0; nt < 4; nt++)
          acc2[mt][nt] = __builtin_amdgcn_mfma_f32_16x16x32_bf16(uf[mt], vf[k0][nt], acc2[mt][nt], 0, 0, 0);
    }
  }
  // store ctx partials bf16: part[z][m][d]
  const long zp = (long)(bh * 16 + ck);
#pragma unroll
  for (int mt = 0; mt < 4; mt++)
#pragma unroll
    for (int nt = 0; nt < 4; nt++)
#pragma unroll
      for (int r = 0; r < 4; r++) {
        int m = w * 64 + mt * 16 + g * 4 + r;
        int d = nt * 16 + c;
        part[(zp * NF + m) * HD + d] = f2bf(acc2[mt][nt][r]);
      }
  // su atomic (reduce over lane groups sharing c)
#pragma unroll
  for (int nt = 0; nt < 4; nt++) {
    float v = suv[nt];
    v += __shfl_xor(v, 16);
    v += __shfl_xor(v, 32);
    if (l < 16) atomicAdd(&su[bh * NF + w * 64 + nt * 16 + l], v);
  }
  for (int o = 32; o; o >>= 1) amax = fmaxf(amax, __shfl_xor(amax, o));
  if (l == 0) atomicMax(stabEnc, encf(c1f() * amax));
}

// ---------------------------------------------------------------------------
// Fused query features + attention. One block per (64-token tile, bh).
// R4: feature GEMM computes C = [feature][token] (operand-swapped mfma) so
// each lane's natural 4-pack (r) runs along FEATURES = the k-major direction
// of the attention GEMM; q frags direct from global; one barrier, 34KB LDS.
// R6: per-token-granule accumulator strip accC[4] (16 regs, recycled per nt)
// replaces the persistent acc[4][4] (64 regs) that spilled under (256,4):
// peak live ~116 unified regs < 128 -> 4 waves/SIMD, no scratch.
// ---------------------------------------------------------------------------
__global__ __launch_bounds__(256, 4) void k_fq_attn(const u16* __restrict__ qb, const u16* __restrict__ projb,
                                                    const float* __restrict__ k_sum, const float* __restrict__ ksum_tot,
                                                    const u16* __restrict__ ct_bf, const float* __restrict__ ctsum,
                                                    u16* __restrict__ attn_bf) {
  __shared__ __align__(16) u16 sUq[64 * 256];    // Uq [token][m], 16B-granule swizzled
  __shared__ float redmax[4][64];
  __shared__ float redsum[4][64];
  const int bh = blockIdx.y, b = bh >> 4, h = bh & 15;
  const long t0 = (long)b * SEQ + blockIdx.x * 64;
  const int tid = threadIdx.x, w = tid >> 6, l = tid & 63;
  const int lrow = l & 15, lk = (l >> 4) * 8, lr4 = (l >> 4) * 4, lc = l & 15;

  // A-frags: proj rows = features w*64+mt*16+lrow, k = k0*32+lk+j
  bf16x8 pf[4][2];
#pragma unroll
  for (int mt = 0; mt < 4; mt++)
#pragma unroll
    for (int k0 = 0; k0 < 2; k0++)
      pf[mt][k0] = *(const bf16x8*)&projb[(w * 64 + mt * 16 + lrow) * 64 + k0 * 32 + lk];
  // B-frags: q rows = tokens nt*16+lrow (direct from global, fk_ctx pattern).
  // All loads issued upfront so HBM latency overlaps the diag + first GEMMs.
  bf16x8 af[4][2];
#pragma unroll
  for (int nt = 0; nt < 4; nt++)
#pragma unroll
    for (int k0 = 0; k0 < 2; k0++)
      af[nt][k0] = *(const bf16x8*)&qb[(t0 + nt * 16 + lrow) * EMB + h * HD + k0 * 32 + lk];

  // inline diag per token: each lane ends with diag of its OWN token nt*16+lc
  float dgq[4];
#pragma unroll
  for (int nt = 0; nt < 4; nt++) {
    float ss = 0.f;
#pragma unroll
    for (int k0 = 0; k0 < 2; k0++)
#pragma unroll
      for (int j = 0; j < 8; j++) {
        float v = bf2f((u16)af[nt][k0][j]);
        ss += v * v;
      }
    ss += __shfl_xor(ss, 16);
    ss += __shfl_xor(ss, 32);
    dgq[nt] = ss * 0.0625f;
  }

  // k_sum for this lane's 16 features (mt, lr4+r)
  f32x4 ksr[4];
#pragma unroll
  for (int mt = 0; mt < 4; mt++)
    ksr[mt] = *(const f32x4*)&k_sum[(long)bh * NF + w * 64 + mt * 16 + lr4];

  // per-token-granule nt: 16-col strip of the feature GEMM (accC recycled)
  // + epilogue: U -> sUq (u16x4 along features, swizzled), per-token max,
  // sum(U*ksum) partials.
#pragma unroll
  for (int nt = 0; nt < 4; nt++) {
    f32x4 accC[4];
#pragma unroll
    for (int mt = 0; mt < 4; mt++) accC[mt] = (f32x4)0.0f;
#pragma unroll
    for (int k0 = 0; k0 < 2; k0++)
#pragma unroll
      for (int mt = 0; mt < 4; mt++)
        accC[mt] = __builtin_amdgcn_mfma_f32_16x16x32_bf16(pf[mt][k0], af[nt][k0], accC[mt], 0, 0, 0);

    const int tok = nt * 16 + lc;
    const int trow = tok * NF, tsw = tok & 7;
    float vmax = -1e30f, s = 0.f;
#pragma unroll
    for (int mt = 0; mt < 4; mt++) {
      const int fb = w * 64 + mt * 16 + lr4;   // multiple of 4
      u16x4 pk;
#pragma unroll
      for (int r = 0; r < 4; r++) {
        float dd = c1f() * accC[mt][r];
        vmax = fmaxf(vmax, dd);
        float U = __expf(dd - dgq[nt]);
        pk[r] = f2bf(U);
        s += U * ksr[mt][r];
      }
      *(u16x4*)&sUq[trow + (((fb >> 3) ^ tsw) << 3) + (fb & 7)] = pk;
    }
    vmax = fmaxf(vmax, __shfl_xor(vmax, 16));
    vmax = fmaxf(vmax, __shfl_xor(vmax, 32));
    s += __shfl_xor(s, 16);
    s += __shfl_xor(s, 32);
    if (l < 16) { redmax[w][nt * 16 + l] = vmax; redsum[w][nt * 16 + l] = s; }
  }
  __syncthreads();
  // attention GEMM: wave w owns d in [w*16, w*16+16); K = 256 features
  f32x4 acc2[4];
#pragma unroll
  for (int mt = 0; mt < 4; mt++) acc2[mt] = (f32x4)0.0f;
#pragma unroll
  for (int kk = 0; kk < 8; kk++) {
    bf16x8 bfr = *(const bf16x8*)&ct_bf[((long)bh * HD + w * 16 + lrow) * NF + kk * 32 + lk];
#pragma unroll
    for (int mt = 0; mt < 4; mt++) {
      int row = mt * 16 + lrow;
      bf16x8 a2 = *(const bf16x8*)&sUq[row * NF + (((kk * 4 + (l >> 4)) ^ (row & 7)) * 8)];
      acc2[mt] = __builtin_amdgcn_mfma_f32_16x16x32_bf16(a2, bfr, acc2[mt], 0, 0, 0);
    }
  }
  // epilogue: alpha/beta per row, write bf16 attn in [B,N,E]
  const float kst = ksum_tot[bh];
  const float cts = ctsum[(long)bh * HD + w * 16 + lc];
#pragma unroll
  for (int mt = 0; mt < 4; mt++)
#pragma unroll
    for (int r = 0; r < 4; r++) {
      int row = mt * 16 + lr4 + r;
      float rs = fmaxf(fmaxf(redmax[0][row], redmax[1][row]),
                       fmaxf(redmax[2][row], redmax[3][row]));
      float S1 = redsum[0][row] + redsum[1][row] + redsum[2][row] + redsum[3][row];
      float ers = __expf(-rs);
      float di = 1.0f / (ratf() * (ers * S1 + kepsf() * kst));
      float a_ = di * ratf() * ers;
      float b_ = di * ratf() * kepsf();
      float ov = a_ * acc2[mt][r] + b_ * cts;
      attn_bf[(t0 + row) * EMB + h * HD + w * 16 + lc] = f2bf(ov);
    }
}

// --------------------------- glue kernels ----------------------------------
__global__ void k_cvt(const float* __restrict__ s, u16* __restrict__ d, long n4) {
  long i = (long)blockIdx.x * blockDim.x + threadIdx.x;
  if (i >= n4) return;
  float4 v = ((const float4*)s)[i];
  u16x4 o = { f2bf(v.x), f2bf(v.y), f2bf(v.z), f2bf(v.w) };
  ((u16x4*)d)[i] = o;
}

__global__ void k_init(float* su, float* vsum, u32* stabEnc) {
  int i = blockIdx.x * 256 + threadIdx.x;
  if (i < BHN * NF) su[i] = 0.f;
  if (i < BHN * HD) vsum[i] = 0.f;
  if (i == 0) *stabEnc = 0u;
}

// k_sum[m] = ratio*(e^-stab*su[m] + eps*SEQ); ksum_tot = sum_m k_sum
__global__ __launch_bounds__(256) void k_asm_ksum(const float* __restrict__ su, const u32* __restrict__ stabEnc,
                                                  float* __restrict__ k_sum, float* __restrict__ ksum_tot) {
  __shared__ float red[256];
  int z = blockIdx.x, m = threadIdx.x;
  float es = __expf(-decf(*stabEnc));
  float v = ratf() * (es * su[(long)z * NF + m] + kepsf() * (float)SEQ);
  k_sum[(long)z * NF + m] = v;
  red[m] = v;
  __syncthreads();
  for (int s = 128; s > 0; s >>= 1) {
    if (m < s) red[m] += red[m + s];
    __syncthreads();
  }
  if (m == 0) ksum_tot[z] = red[0];
}

// ct[d][m] = ratio*(e^-stab*sum_ck part[m][d] + eps*vsum[d]) -> bf16; ctsum[d]
__global__ __launch_bounds__(256) void k_asm_ct(const u16* __restrict__ part, const float* __restrict__ vsum,
                                                const u32* __restrict__ stabEnc, u16* __restrict__ ct_bf,
                                                float* __restrict__ ctsum) {
  __shared__ float red[4][64];
  const int z = blockIdx.x, tid = threadIdx.x;
  const int w = tid >> 6, l = tid & 63;
  float es = __expf(-decf(*stabEnc));
  float vs = vsum[(long)z * HD + l];
  float csum = 0.f;
  for (int m = w; m < NF; m += 4) {
    float a = 0.f;
#pragma unroll
    for (int ck = 0; ck < 16; ck++)
      a += bf2f(part[((long)(z * 16 + ck) * NF + m) * HD + l]);
    float cv = ratf() * (es * a + kepsf() * vs);
    ct_bf[((long)z * HD + l) * NF + m] = f2bf(cv);
    csum += cv;
  }
  red[w][l] = csum;
  __syncthreads();
  if (tid < 64)
    ctsum[(long)z * HD + tid] = red[0][tid] + red[1][tid] + red[2][tid] + red[3][tid];
}

// ---------------------------------------------------------------------------
extern "C" void kernel_launch(void* const* d_in, const int* in_sizes, int n_in,
                              void* d_out, int out_size, void* d_ws, size_t ws_size,
                              hipStream_t stream) {
  const float* x    = (const float*)d_in[0];
  const float* Wq   = (const float*)d_in[1];
  const float* bq   = (const float*)d_in[2];
  const float* Wk   = (const float*)d_in[3];
  const float* bk   = (const float*)d_in[4];
  const float* Wv   = (const float*)d_in[5];
  const float* bv   = (const float*)d_in[6];
  const float* Wo   = (const float*)d_in[7];
  const float* bo   = (const float*)d_in[8];
  const float* proj = (const float*)d_in[9];

  char* base = (char*)d_ws;
  size_t off = 0;
  auto alloc = [&](size_t bytes) {
    off = (off + 255) & ~(size_t)255;
    char* r = base + off;
    off += bytes;
    return r;
  };
  // total ~153 MB (unchanged from passing round-2 layout)
  u16*  xb     = (u16*)alloc((size_t)TOKN * EMB * 2);   // 33.5 MB, reused as 'part'
  u16*  wqb    = (u16*)alloc((size_t)EMB * EMB * 2);
  u16*  wkb    = (u16*)alloc((size_t)EMB * EMB * 2);
  u16*  wvb    = (u16*)alloc((size_t)EMB * EMB * 2);
  u16*  wob    = (u16*)alloc((size_t)EMB * EMB * 2);
  u16*  projb  = (u16*)alloc((size_t)NF * HD * 2);
  u16*  qb     = (u16*)alloc((size_t)TOKN * EMB * 2);   // 33.5 MB
  u16*  kb     = (u16*)alloc((size_t)TOKN * EMB * 2);   // 33.5 MB, reused as attn_bf
  u16*  vb     = (u16*)alloc((size_t)TOKN * EMB * 2);   // 33.5 MB
  float* su    = (float*)alloc((size_t)BHN * NF * 4);
  float* k_sum = (float*)alloc((size_t)BHN * NF * 4);
  float* ksum_t= (float*)alloc((size_t)BHN * 4);
  float* vsum  = (float*)alloc((size_t)BHN * HD * 4);
  float* ctsum = (float*)alloc((size_t)BHN * HD * 4);
  u32*  stabE  = (u32*)alloc(256);
  u16*  ct_bf  = (u16*)alloc((size_t)BHN * HD * NF * 2); // 2 MB
  u16*  part   = xb;          // alias: xb dead after QKV GEMMs (bf16, exact fit)
  u16*  attn_bf= kb;          // alias: kb dead after k_fk_ctx
  u16*  vT     = (u16*)d_out; // alias: d_out scratch until final GEMM (33.5 of 67 MB)

  // 0. init atomic accumulators
  k_init<<<64, 256, 0, stream>>>(su, vsum, stabE);
  // 1. fp32 -> bf16
  k_cvt<<<(TOKN * EMB / 4 + 255) / 256, 256, 0, stream>>>(x, xb, (long)TOKN * EMB / 4);
  k_cvt<<<(EMB * EMB / 4 + 255) / 256, 256, 0, stream>>>(Wq, wqb, (long)EMB * EMB / 4);
  k_cvt<<<(EMB * EMB / 4 + 255) / 256, 256, 0, stream>>>(Wk, wkb, (long)EMB * EMB / 4);
  k_cvt<<<(EMB * EMB / 4 + 255) / 256, 256, 0, stream>>>(Wv, wvb, (long)EMB * EMB / 4);
  k_cvt<<<(EMB * EMB / 4 + 255) / 256, 256, 0, stream>>>(Wo, wob, (long)EMB * EMB / 4);
  k_cvt<<<(NF * HD / 4 + 255) / 256, 256, 0, stream>>>(proj, projb, (long)NF * HD / 4);
  // 2. QKV projections
  dim3 gq(EMB / 128, TOKN / 128);
  k_gemm<true><<<gq, 256, 0, stream>>>(xb, wqb, qb, bq, EMB, EMB, EMB, EMB);
  k_gemm<true><<<gq, 256, 0, stream>>>(xb, wkb, kb, bk, EMB, EMB, EMB, EMB);
  k_gemm<true><<<gq, 256, 0, stream>>>(xb, wvb, vb, bv, EMB, EMB, EMB, EMB);
  // 3. v transpose into d_out scratch + vsum
  k_vT<<<dim3(SEQ / 64, BHN), 256, 0, stream>>>(vb, vT, vsum);
  // 4. fused key features + context partials (writes part=xb after xb dead)
  k_fk_ctx<<<dim3(16, BHN), 256, 0, stream>>>(kb, vT, projb, part, su, stabE);
  // 5. assemble k_sum / ksum_tot
  k_asm_ksum<<<BHN, 256, 0, stream>>>(su, stabE, k_sum, ksum_t);
  // 6. assemble context (bf16) + ctsum
  k_asm_ct<<<BHN, 256, 0, stream>>>(part, vsum, stabE, ct_bf, ctsum);
  // 7. fused query features + attention (writes attn_bf=kb after kb dead)
  k_fq_attn<<<dim3(SEQ / 64, BHN), 256, 0, stream>>>(qb, projb, k_sum, ksum_t, ct_bf, ctsum, attn_bf);
  // 8. output projection (fp32 out, overwrites vT scratch region)
  k_gemm<false><<<gq, 256, 0, stream>>>(attn_bf, wob, d_out, bo, EMB, EMB, EMB, EMB);
}

// Round 10
// 560.721 us; speedup vs baseline: 1.4326x; 1.4326x over previous
//
#include <hip/hip_runtime.h>
#include <hip/hip_bf16.h>
#include <stdint.h>

// Performer (FAVOR+) forward, MI355X/gfx950.
// B=4, N=4096, E=1024, H=16, D=64, M(features)=256.
// bf16 MFMA (16x16x32) everywhere matmul-shaped, fp32 accumulate/epilogues.
// kf never materialized: kf = ratio*(e^-stab * U + eps), U = exp(dd-diag) is
// stab-free; context/k_sum assembled linearly from fused U^T·v and U^T·1.
// R3: k_fk_ctx barrier-free (per-wave sU, direct global frags, vT scratch).
// R4: k_fq_attn operand-swapped feature GEMM; XCD swizzle on k_gemm.
// R5: k_fk_ctx per-token-granule accR strip. MEASURED: 85.5 -> 74 us.
// R6: k_fq_attn spill fix (accC strip). MEASURED: total 578 -> 563 us.
// R7 FAILED: (256,3) cap squeezed allocator -> spill (WRITE 119MB), 133 us.
// R8 FAILED: 8-wave split + (512,4) -> 64-reg budget -> spill (169MB), 166 us.
// R9 FAILED: afA/afB ping-pong via conditional REFERENCE select defeated
// SROA -> both buffers in scratch (WRITE 392MB), 267 us. Rule #20.
// R10: PURE REVERT to the measured R6 build (562.8 us). k_fk_ctx is CLOSED
// at 74 us: demand ~176 regs sits in the (128,256] occupancy bucket ->
// 2 waves/SIMD structurally; every squeeze attempt spilled. Next target:
// the k_gemm aggregate (~240 us across 4 dispatches).

#define TOKN  16384
#define SEQ   4096
#define EMB   1024
#define NHEAD 16
#define HD    64
#define NF    256
#define BHN   64   // batch*heads

static __device__ __forceinline__ constexpr float c1f()  { return 0.35355339059327379f; } // 64^-0.25
static __device__ __forceinline__ constexpr float ratf() { return 0.0625f; }              // 256^-0.5
static __device__ __forceinline__ constexpr float kepsf(){ return 1e-4f; }

typedef unsigned short u16;
typedef unsigned int   u32;
typedef __attribute__((ext_vector_type(8))) short bf16x8;
typedef __attribute__((ext_vector_type(4))) float f32x4;
typedef __attribute__((ext_vector_type(4))) u16   u16x4;

union U8 { bf16x8 v8; u16x4 q[2]; };

__device__ __forceinline__ float bf2f(u16 u) { return __uint_as_float(((u32)u) << 16); }
__device__ __forceinline__ u16 f2bf(float f) {
  u32 u = __float_as_uint(f);
  u += 0x7fffu + ((u >> 16) & 1u);   // RNE
  return (u16)(u >> 16);
}
// order-preserving float<->uint encoding for atomicMax on a float
__device__ __forceinline__ u32 encf(float f) {
  u32 u = __float_as_uint(f);
  return (u & 0x80000000u) ? ~u : (u | 0x80000000u);
}
__device__ __forceinline__ float decf(u32 e) {
  u32 u = (e & 0x80000000u) ? (e & 0x7fffffffu) : ~e;
  return __uint_as_float(u);
}

__device__ __forceinline__ void gl2lds16(const u16* g, void* l) {
  __builtin_amdgcn_global_load_lds(
      (const __attribute__((address_space(1))) u32*)g,
      (__attribute__((address_space(3))) u32*)l, 16, 0, 0);
}

#define ZERO_ACC(acc)                         \
  _Pragma("unroll") for (int _i = 0; _i < 4; _i++) \
  _Pragma("unroll") for (int _j = 0; _j < 4; _j++) acc[_i][_j] = (f32x4)0.0f;

// ---------------------------------------------------------------------------
// m97-style MFMA GEMM core: C[m][n] += sum_k A[m][k]*B[n][k] (both row-major,
// K contiguous). 256 thr = 4 waves; wave tile 64x64 (4x4 of 16x16x32). BK=32.
// ---------------------------------------------------------------------------
template <int BM, int BN>
__device__ __forceinline__ void gemm_core(const u16* __restrict__ Ag, long lda,
                                          const u16* __restrict__ Bg, long ldb,
                                          int K, u16* sA, u16* sB,
                                          f32x4 (&acc)[4][4]) {
  const int tid = threadIdx.x;
  const int w = tid >> 6, l = tid & 63;
  constexpr int WM = BM / 64;
  const int wm = w % WM, wn = w / WM;
  const int lrow = l & 15, lk = (l >> 4) * 8;
  constexpr int AI = (BM * 4) / 256;
  constexpr int BI = (BN * 4) / 256;

  for (int k0 = 0; k0 < K; k0 += 32) {
    __syncthreads();
#pragma unroll
    for (int i = 0; i < AI; i++) {
      int q = i * 256 + tid;
      gl2lds16(Ag + (long)(q >> 2) * lda + k0 + (q & 3) * 8,
               (char*)sA + i * 4096 + w * 1024);
    }
#pragma unroll
    for (int i = 0; i < BI; i++) {
      int q = i * 256 + tid;
      gl2lds16(Bg + (long)(q >> 2) * ldb + k0 + (q & 3) * 8,
               (char*)sB + i * 4096 + w * 1024);
    }
    __syncthreads();
    bf16x8 af[4], bfr[4];
#pragma unroll
    for (int mt = 0; mt < 4; mt++)
      af[mt] = *(const bf16x8*)(sA + ((wm * 64 + mt * 16 + lrow) * 32 + lk));
#pragma unroll
    for (int nt = 0; nt < 4; nt++)
      bfr[nt] = *(const bf16x8*)(sB + ((wn * 64 + nt * 16 + lrow) * 32 + lk));
#pragma unroll
    for (int mt = 0; mt < 4; mt++)
#pragma unroll
      for (int nt = 0; nt < 4; nt++)
        acc[mt][nt] = __builtin_amdgcn_mfma_f32_16x16x32_bf16(af[mt], bfr[nt], acc[mt][nt], 0, 0, 0);
  }
}

// ---------------------------------------------------------------------------
// Big 128x128 GEMM: C = A*B^T + bias. XCD-aware block swizzle: consecutive
// groups of nwg/8 tiles land on one XCD so an A-panel's 8 column-tiles share
// that XCD's private L2 (A slice/XCD = 4MB = L2 size) instead of streaming
// the full 32MB A through every XCD L2.
// ---------------------------------------------------------------------------
template <bool BF16OUT>
__global__ __launch_bounds__(256) void k_gemm(const u16* __restrict__ A, const u16* __restrict__ Bw,
                                              void* __restrict__ Cout, const float* __restrict__ bias,
                                              int K, int lda, int ldb, int ldc) {
  __shared__ __align__(16) u16 sA[128 * 32];
  __shared__ __align__(16) u16 sB[128 * 32];
  const int nbx = gridDim.x;
  const int nwg = nbx * gridDim.y;
  int lin = blockIdx.y * nbx + blockIdx.x;
  if ((nwg & 7) == 0) {                    // bijective XCD swizzle (nwg%8==0)
    int per = nwg >> 3;
    lin = (lin & 7) * per + (lin >> 3);
  }
  const int m0 = (lin / nbx) * 128, n0 = (lin % nbx) * 128;
  f32x4 acc[4][4]; ZERO_ACC(acc);
  gemm_core<128, 128>(A + (long)m0 * lda, lda, Bw + (long)n0 * ldb, ldb, K, sA, sB, acc);
  const int l = threadIdx.x & 63, w = threadIdx.x >> 6;
  const int wm = w & 1, wn = w >> 1, lr4 = (l >> 4) * 4, lc = l & 15;
#pragma unroll
  for (int nt = 0; nt < 4; nt++) {
    int gcol = n0 + wn * 64 + nt * 16 + lc;
    float bia = bias[gcol];
#pragma unroll
    for (int mt = 0; mt < 4; mt++)
#pragma unroll
      for (int r = 0; r < 4; r++) {
        int grow = m0 + wm * 64 + mt * 16 + lr4 + r;
        float v = acc[mt][nt][r] + bia;
        if (BF16OUT) ((u16*)Cout)[(long)grow * ldc + gcol] = f2bf(v);
        else         ((float*)Cout)[(long)grow * ldc + gcol] = v;
      }
  }
}

// ---------------------------------------------------------------------------
// v transpose: vb [B,N,E] head-sliced -> vT[bh][d][n] (bf16), plus vsum[bh][d].
// ---------------------------------------------------------------------------
__global__ __launch_bounds__(256) void k_vT(const u16* __restrict__ vb, u16* __restrict__ vT,
                                            float* __restrict__ vsum) {
  __shared__ u16 t[64][72];   // 72 stride: 8B-aligned rows, conflict-benign
  const int bh = blockIdx.y, n0 = blockIdx.x * 64, b = bh >> 4, h = bh & 15;
  const int tid = threadIdx.x;
#pragma unroll
  for (int i = 0; i < 2; i++) {
    int idx = i * 256 + tid, row = idx >> 3, c8 = idx & 7;
    U8 u;
    u.v8 = *(const bf16x8*)&vb[((long)(b * SEQ) + n0 + row) * EMB + h * HD + c8 * 8];
    *(u16x4*)&t[row][c8 * 8]     = u.q[0];
    *(u16x4*)&t[row][c8 * 8 + 4] = u.q[1];
  }
  __syncthreads();
  const int nq = tid & 15, dh = tid >> 4;
#pragma unroll
  for (int i = 0; i < 4; i++) {
    int d = i * 16 + dh;
    u16x4 pk; float s = 0.f;
#pragma unroll
    for (int j = 0; j < 4; j++) { u16 v = t[nq * 4 + j][d]; pk[j] = v; s += bf2f(v); }
    *(u16x4*)&vT[((long)bh * HD + d) * SEQ + n0 + nq * 4] = pk;
    s += __shfl_xor(s, 1); s += __shfl_xor(s, 2);
    s += __shfl_xor(s, 4); s += __shfl_xor(s, 8);
    if (nq == 0) atomicAdd(&vsum[bh * HD + d], s);
  }
}

// ---------------------------------------------------------------------------
// Fused key features + context partials, BARRIER-FREE.
// Grid (16 chunks, 64 bh); block = 256 tokens in 4 sub-tiles of 64.
// A-frags (k) and B-frags (vT) direct from global; U transposed through a
// per-wave 8KB LDS region (intra-wave only -> no __syncthreads at all).
// part[z=bh*16+ck][m=256][d=64] bf16. su/stab via atomics.
// R5: feature GEMM per-token-granule (accR[4] recycled, 16 regs) so only one
// 64-reg accumulator (acc2) is persistent -> 2 waves/SIMD. CLOSED at 74 us.
// ---------------------------------------------------------------------------
__global__ __launch_bounds__(256, 2) void k_fk_ctx(const u16* __restrict__ kb, const u16* __restrict__ vT,
                                                   const u16* __restrict__ projb, u16* __restrict__ part,
                                                   float* __restrict__ su, u32* __restrict__ stabEnc) {
  __shared__ __align__(16) u16 sU[4][64 * 64];   // per-wave 8KB regions
  const int ck = blockIdx.x, bh = blockIdx.y, b = bh >> 4, h = bh & 15;
  const int tid = threadIdx.x, w = tid >> 6, l = tid & 63;
  const int c = l & 15, g = l >> 4;
  u16* sUw = &sU[w][0];
  const int sw = c & 7;

  // proj B-fragments in registers: features w*64+nt*16+c, k = k0*32+g*8+j
  bf16x8 pf[4][2];
#pragma unroll
  for (int nt = 0; nt < 4; nt++)
#pragma unroll
    for (int k0 = 0; k0 < 2; k0++)
      pf[nt][k0] = *(const bf16x8*)&projb[(w * 64 + nt * 16 + c) * 64 + k0 * 32 + g * 8];

  f32x4 acc2[4][4]; ZERO_ACC(acc2);   // ctx: rows=features(wave-local), cols=d
  float suv[4] = {0.f, 0.f, 0.f, 0.f};
  float amax = -1e30f;                // max raw acc; stab = c1*amax (monotone)
  const long tok0 = (long)b * SEQ + ck * 256;

  for (int s = 0; s < 4; s++) {
    const long t0 = tok0 + s * 64;
    // A-fragments direct from global: token = mt*16+c, k(d) = k0*32+g*8+j
    bf16x8 af[4][2];
#pragma unroll
    for (int mt = 0; mt < 4; mt++)
#pragma unroll
      for (int k0 = 0; k0 < 2; k0++)
        af[mt][k0] = *(const bf16x8*)&kb[(t0 + mt * 16 + c) * EMB + h * HD + k0 * 32 + g * 8];
    // hoist vT B-frags for the ctx GEMM: HBM/L3 latency hides under the
    // feature GEMM + epilogue below.
    bf16x8 vf[2][4];
#pragma unroll
    for (int k0 = 0; k0 < 2; k0++)
#pragma unroll
      for (int nt = 0; nt < 4; nt++)
        vf[k0][nt] = *(const bf16x8*)&vT[((long)bh * HD + nt * 16 + c) * SEQ +
                                         ck * 256 + s * 64 + k0 * 32 + g * 8];

    // per-token-granule mt: diag + one 16-row strip of the feature GEMM +
    // epilogue, with accR recycled (peak acc pressure 64+16 not 64+64).
#pragma unroll
    for (int mt = 0; mt < 4; mt++) {
      float ss = 0.f;
#pragma unroll
      for (int k0 = 0; k0 < 2; k0++)
#pragma unroll
        for (int j = 0; j < 8; j++) {
          float v = bf2f((u16)af[mt][k0][j]);
          ss += v * v;
        }
      ss += __shfl_xor(ss, 16);
      ss += __shfl_xor(ss, 32);
      const float dgrow = ss * 0.0625f;   // diag of token mt*16+c
      f32x4 accR[4];
#pragma unroll
      for (int nt = 0; nt < 4; nt++) accR[nt] = (f32x4)0.0f;
#pragma unroll
      for (int k0 = 0; k0 < 2; k0++)
#pragma unroll
        for (int nt = 0; nt < 4; nt++)
          accR[nt] = __builtin_amdgcn_mfma_f32_16x16x32_bf16(af[mt][k0], pf[nt][k0], accR[nt], 0, 0, 0);
      // epilogue: U = exp(c1*acc - diag) -> per-wave sU (swizzled), su, stab
      float dg[4];
#pragma unroll
      for (int r = 0; r < 4; r++) dg[r] = __shfl(dgrow, g * 4 + r);
#pragma unroll
      for (int nt = 0; nt < 4; nt++) {
        u16x4 pk;
#pragma unroll
        for (int r = 0; r < 4; r++) {
          float a = accR[nt][r];
          amax = fmaxf(amax, a);
          float U = __expf(fmaf(a, c1f(), -dg[r]));
          pk[r] = f2bf(U);
          suv[nt] += U;
        }
        // write tokens granule G=mt*4+g (pair P=mt*2+(g>>1), b=g&1), row nt*16+c
        *(u16x4*)&sUw[(nt * 16 + c) * 64 + (((mt * 2 + (g >> 1)) ^ sw) * 2 + (g & 1)) * 4] = pk;
      }
    }
    // ctx GEMM: acc2[m][d] += sum_n U^T[m][n] * vT[d][n]  (intra-wave sU reads)
#pragma unroll
    for (int k0 = 0; k0 < 2; k0++) {
      bf16x8 uf[4];
#pragma unroll
      for (int mt = 0; mt < 4; mt++)
        uf[mt] = *(const bf16x8*)&sUw[(mt * 16 + c) * 64 + ((k0 * 4 + g) ^ sw) * 8];
#pragma unroll
      for (int mt = 0; mt < 4; mt++)
#pragma unroll
        for (int nt = 0; nt < 4; nt++)
          acc2[mt][nt] = __builtin_amdgcn_mfma_f32_16x16x32_bf16(uf[mt], vf[k0][nt], acc2[mt][nt], 0, 0, 0);
    }
  }
  // store ctx partials bf16: part[z][m][d]
  const long zp = (long)(bh * 16 + ck);
#pragma unroll
  for (int mt = 0; mt < 4; mt++)
#pragma unroll
    for (int nt = 0; nt < 4; nt++)
#pragma unroll
      for (int r = 0; r < 4; r++) {
        int m = w * 64 + mt * 16 + g * 4 + r;
        int d = nt * 16 + c;
        part[(zp * NF + m) * HD + d] = f2bf(acc2[mt][nt][r]);
      }
  // su atomic (reduce over lane groups sharing c)
#pragma unroll
  for (int nt = 0; nt < 4; nt++) {
    float v = suv[nt];
    v += __shfl_xor(v, 16);
    v += __shfl_xor(v, 32);
    if (l < 16) atomicAdd(&su[bh * NF + w * 64 + nt * 16 + l], v);
  }
  for (int o = 32; o; o >>= 1) amax = fmaxf(amax, __shfl_xor(amax, o));
  if (l == 0) atomicMax(stabEnc, encf(c1f() * amax));
}

// ---------------------------------------------------------------------------
// Fused query features + attention. One block per (64-token tile, bh).
// R4: feature GEMM computes C = [feature][token] (operand-swapped mfma) so
// each lane's natural 4-pack (r) runs along FEATURES = the k-major direction
// of the attention GEMM; q frags direct from global; one barrier, 34KB LDS.
// R6: per-token-granule accumulator strip accC[4] (16 regs, recycled per nt)
// replaces the persistent acc[4][4] (64 regs) that spilled under (256,4):
// peak live ~116 unified regs < 128 -> 4 waves/SIMD, no scratch.
// ---------------------------------------------------------------------------
__global__ __launch_bounds__(256, 4) void k_fq_attn(const u16* __restrict__ qb, const u16* __restrict__ projb,
                                                    const float* __restrict__ k_sum, const float* __restrict__ ksum_tot,
                                                    const u16* __restrict__ ct_bf, const float* __restrict__ ctsum,
                                                    u16* __restrict__ attn_bf) {
  __shared__ __align__(16) u16 sUq[64 * 256];    // Uq [token][m], 16B-granule swizzled
  __shared__ float redmax[4][64];
  __shared__ float redsum[4][64];
  const int bh = blockIdx.y, b = bh >> 4, h = bh & 15;
  const long t0 = (long)b * SEQ + blockIdx.x * 64;
  const int tid = threadIdx.x, w = tid >> 6, l = tid & 63;
  const int lrow = l & 15, lk = (l >> 4) * 8, lr4 = (l >> 4) * 4, lc = l & 15;

  // A-frags: proj rows = features w*64+mt*16+lrow, k = k0*32+lk+j
  bf16x8 pf[4][2];
#pragma unroll
  for (int mt = 0; mt < 4; mt++)
#pragma unroll
    for (int k0 = 0; k0 < 2; k0++)
      pf[mt][k0] = *(const bf16x8*)&projb[(w * 64 + mt * 16 + lrow) * 64 + k0 * 32 + lk];
  // B-frags: q rows = tokens nt*16+lrow (direct from global, fk_ctx pattern).
  // All loads issued upfront so HBM latency overlaps the diag + first GEMMs.
  bf16x8 af[4][2];
#pragma unroll
  for (int nt = 0; nt < 4; nt++)
#pragma unroll
    for (int k0 = 0; k0 < 2; k0++)
      af[nt][k0] = *(const bf16x8*)&qb[(t0 + nt * 16 + lrow) * EMB + h * HD + k0 * 32 + lk];

  // inline diag per token: each lane ends with diag of its OWN token nt*16+lc
  float dgq[4];
#pragma unroll
  for (int nt = 0; nt < 4; nt++) {
    float ss = 0.f;
#pragma unroll
    for (int k0 = 0; k0 < 2; k0++)
#pragma unroll
      for (int j = 0; j < 8; j++) {
        float v = bf2f((u16)af[nt][k0][j]);
        ss += v * v;
      }
    ss += __shfl_xor(ss, 16);
    ss += __shfl_xor(ss, 32);
    dgq[nt] = ss * 0.0625f;
  }

  // k_sum for this lane's 16 features (mt, lr4+r)
  f32x4 ksr[4];
#pragma unroll
  for (int mt = 0; mt < 4; mt++)
    ksr[mt] = *(const f32x4*)&k_sum[(long)bh * NF + w * 64 + mt * 16 + lr4];

  // per-token-granule nt: 16-col strip of the feature GEMM (accC recycled)
  // + epilogue: U -> sUq (u16x4 along features, swizzled), per-token max,
  // sum(U*ksum) partials.
#pragma unroll
  for (int nt = 0; nt < 4; nt++) {
    f32x4 accC[4];
#pragma unroll
    for (int mt = 0; mt < 4; mt++) accC[mt] = (f32x4)0.0f;
#pragma unroll
    for (int k0 = 0; k0 < 2; k0++)
#pragma unroll
      for (int mt = 0; mt < 4; mt++)
        accC[mt] = __builtin_amdgcn_mfma_f32_16x16x32_bf16(pf[mt][k0], af[nt][k0], accC[mt], 0, 0, 0);

    const int tok = nt * 16 + lc;
    const int trow = tok * NF, tsw = tok & 7;
    float vmax = -1e30f, s = 0.f;
#pragma unroll
    for (int mt = 0; mt < 4; mt++) {
      const int fb = w * 64 + mt * 16 + lr4;   // multiple of 4
      u16x4 pk;
#pragma unroll
      for (int r = 0; r < 4; r++) {
        float dd = c1f() * accC[mt][r];
        vmax = fmaxf(vmax, dd);
        float U = __expf(dd - dgq[nt]);
        pk[r] = f2bf(U);
        s += U * ksr[mt][r];
      }
      *(u16x4*)&sUq[trow + (((fb >> 3) ^ tsw) << 3) + (fb & 7)] = pk;
    }
    vmax = fmaxf(vmax, __shfl_xor(vmax, 16));
    vmax = fmaxf(vmax, __shfl_xor(vmax, 32));
    s += __shfl_xor(s, 16);
    s += __shfl_xor(s, 32);
    if (l < 16) { redmax[w][nt * 16 + l] = vmax; redsum[w][nt * 16 + l] = s; }
  }
  __syncthreads();
  // attention GEMM: wave w owns d in [w*16, w*16+16); K = 256 features
  f32x4 acc2[4];
#pragma unroll
  for (int mt = 0; mt < 4; mt++) acc2[mt] = (f32x4)0.0f;
#pragma unroll
  for (int kk = 0; kk < 8; kk++) {
    bf16x8 bfr = *(const bf16x8*)&ct_bf[((long)bh * HD + w * 16 + lrow) * NF + kk * 32 + lk];
#pragma unroll
    for (int mt = 0; mt < 4; mt++) {
      int row = mt * 16 + lrow;
      bf16x8 a2 = *(const bf16x8*)&sUq[row * NF + (((kk * 4 + (l >> 4)) ^ (row & 7)) * 8)];
      acc2[mt] = __builtin_amdgcn_mfma_f32_16x16x32_bf16(a2, bfr, acc2[mt], 0, 0, 0);
    }
  }
  // epilogue: alpha/beta per row, write bf16 attn in [B,N,E]
  const float kst = ksum_tot[bh];
  const float cts = ctsum[(long)bh * HD + w * 16 + lc];
#pragma unroll
  for (int mt = 0; mt < 4; mt++)
#pragma unroll
    for (int r = 0; r < 4; r++) {
      int row = mt * 16 + lr4 + r;
      float rs = fmaxf(fmaxf(redmax[0][row], redmax[1][row]),
                       fmaxf(redmax[2][row], redmax[3][row]));
      float S1 = redsum[0][row] + redsum[1][row] + redsum[2][row] + redsum[3][row];
      float ers = __expf(-rs);
      float di = 1.0f / (ratf() * (ers * S1 + kepsf() * kst));
      float a_ = di * ratf() * ers;
      float b_ = di * ratf() * kepsf();
      float ov = a_ * acc2[mt][r] + b_ * cts;
      attn_bf[(t0 + row) * EMB + h * HD + w * 16 + lc] = f2bf(ov);
    }
}

// --------------------------- glue kernels ----------------------------------
__global__ void k_cvt(const float* __restrict__ s, u16* __restrict__ d, long n4) {
  long i = (long)blockIdx.x * blockDim.x + threadIdx.x;
  if (i >= n4) return;
  float4 v = ((const float4*)s)[i];
  u16x4 o = { f2bf(v.x), f2bf(v.y), f2bf(v.z), f2bf(v.w) };
  ((u16x4*)d)[i] = o;
}

__global__ void k_init(float* su, float* vsum, u32* stabEnc) {
  int i = blockIdx.x * 256 + threadIdx.x;
  if (i < BHN * NF) su[i] = 0.f;
  if (i < BHN * HD) vsum[i] = 0.f;
  if (i == 0) *stabEnc = 0u;
}

// k_sum[m] = ratio*(e^-stab*su[m] + eps*SEQ); ksum_tot = sum_m k_sum
__global__ __launch_bounds__(256) void k_asm_ksum(const float* __restrict__ su, const u32* __restrict__ stabEnc,
                                                  float* __restrict__ k_sum, float* __restrict__ ksum_tot) {
  __shared__ float red[256];
  int z = blockIdx.x, m = threadIdx.x;
  float es = __expf(-decf(*stabEnc));
  float v = ratf() * (es * su[(long)z * NF + m] + kepsf() * (float)SEQ);
  k_sum[(long)z * NF + m] = v;
  red[m] = v;
  __syncthreads();
  for (int s = 128; s > 0; s >>= 1) {
    if (m < s) red[m] += red[m + s];
    __syncthreads();
  }
  if (m == 0) ksum_tot[z] = red[0];
}

// ct[d][m] = ratio*(e^-stab*sum_ck part[m][d] + eps*vsum[d]) -> bf16; ctsum[d]
__global__ __launch_bounds__(256) void k_asm_ct(const u16* __restrict__ part, const float* __restrict__ vsum,
                                                const u32* __restrict__ stabEnc, u16* __restrict__ ct_bf,
                                                float* __restrict__ ctsum) {
  __shared__ float red[4][64];
  const int z = blockIdx.x, tid = threadIdx.x;
  const int w = tid >> 6, l = tid & 63;
  float es = __expf(-decf(*stabEnc));
  float vs = vsum[(long)z * HD + l];
  float csum = 0.f;
  for (int m = w; m < NF; m += 4) {
    float a = 0.f;
#pragma unroll
    for (int ck = 0; ck < 16; ck++)
      a += bf2f(part[((long)(z * 16 + ck) * NF + m) * HD + l]);
    float cv = ratf() * (es * a + kepsf() * vs);
    ct_bf[((long)z * HD + l) * NF + m] = f2bf(cv);
    csum += cv;
  }
  red[w][l] = csum;
  __syncthreads();
  if (tid < 64)
    ctsum[(long)z * HD + tid] = red[0][tid] + red[1][tid] + red[2][tid] + red[3][tid];
}

// ---------------------------------------------------------------------------
extern "C" void kernel_launch(void* const* d_in, const int* in_sizes, int n_in,
                              void* d_out, int out_size, void* d_ws, size_t ws_size,
                              hipStream_t stream) {
  const float* x    = (const float*)d_in[0];
  const float* Wq   = (const float*)d_in[1];
  const float* bq   = (const float*)d_in[2];
  const float* Wk   = (const float*)d_in[3];
  const float* bk   = (const float*)d_in[4];
  const float* Wv   = (const float*)d_in[5];
  const float* bv   = (const float*)d_in[6];
  const float* Wo   = (const float*)d_in[7];
  const float* bo   = (const float*)d_in[8];
  const float* proj = (const float*)d_in[9];

  char* base = (char*)d_ws;
  size_t off = 0;
  auto alloc = [&](size_t bytes) {
    off = (off + 255) & ~(size_t)255;
    char* r = base + off;
    off += bytes;
    return r;
  };
  // total ~153 MB (unchanged from passing round-2 layout)
  u16*  xb     = (u16*)alloc((size_t)TOKN * EMB * 2);   // 33.5 MB, reused as 'part'
  u16*  wqb    = (u16*)alloc((size_t)EMB * EMB * 2);
  u16*  wkb    = (u16*)alloc((size_t)EMB * EMB * 2);
  u16*  wvb    = (u16*)alloc((size_t)EMB * EMB * 2);
  u16*  wob    = (u16*)alloc((size_t)EMB * EMB * 2);
  u16*  projb  = (u16*)alloc((size_t)NF * HD * 2);
  u16*  qb     = (u16*)alloc((size_t)TOKN * EMB * 2);   // 33.5 MB
  u16*  kb     = (u16*)alloc((size_t)TOKN * EMB * 2);   // 33.5 MB, reused as attn_bf
  u16*  vb     = (u16*)alloc((size_t)TOKN * EMB * 2);   // 33.5 MB
  float* su    = (float*)alloc((size_t)BHN * NF * 4);
  float* k_sum = (float*)alloc((size_t)BHN * NF * 4);
  float* ksum_t= (float*)alloc((size_t)BHN * 4);
  float* vsum  = (float*)alloc((size_t)BHN * HD * 4);
  float* ctsum = (float*)alloc((size_t)BHN * HD * 4);
  u32*  stabE  = (u32*)alloc(256);
  u16*  ct_bf  = (u16*)alloc((size_t)BHN * HD * NF * 2); // 2 MB
  u16*  part   = xb;          // alias: xb dead after QKV GEMMs (bf16, exact fit)
  u16*  attn_bf= kb;          // alias: kb dead after k_fk_ctx
  u16*  vT     = (u16*)d_out; // alias: d_out scratch until final GEMM (33.5 of 67 MB)

  // 0. init atomic accumulators
  k_init<<<64, 256, 0, stream>>>(su, vsum, stabE);
  // 1. fp32 -> bf16
  k_cvt<<<(TOKN * EMB / 4 + 255) / 256, 256, 0, stream>>>(x, xb, (long)TOKN * EMB / 4);
  k_cvt<<<(EMB * EMB / 4 + 255) / 256, 256, 0, stream>>>(Wq, wqb, (long)EMB * EMB / 4);
  k_cvt<<<(EMB * EMB / 4 + 255) / 256, 256, 0, stream>>>(Wk, wkb, (long)EMB * EMB / 4);
  k_cvt<<<(EMB * EMB / 4 + 255) / 256, 256, 0, stream>>>(Wv, wvb, (long)EMB * EMB / 4);
  k_cvt<<<(EMB * EMB / 4 + 255) / 256, 256, 0, stream>>>(Wo, wob, (long)EMB * EMB / 4);
  k_cvt<<<(NF * HD / 4 + 255) / 256, 256, 0, stream>>>(proj, projb, (long)NF * HD / 4);
  // 2. QKV projections
  dim3 gq(EMB / 128, TOKN / 128);
  k_gemm<true><<<gq, 256, 0, stream>>>(xb, wqb, qb, bq, EMB, EMB, EMB, EMB);
  k_gemm<true><<<gq, 256, 0, stream>>>(xb, wkb, kb, bk, EMB, EMB, EMB, EMB);
  k_gemm<true><<<gq, 256, 0, stream>>>(xb, wvb, vb, bv, EMB, EMB, EMB, EMB);
  // 3. v transpose into d_out scratch + vsum
  k_vT<<<dim3(SEQ / 64, BHN), 256, 0, stream>>>(vb, vT, vsum);
  // 4. fused key features + context partials (writes part=xb after xb dead)
  k_fk_ctx<<<dim3(16, BHN), 256, 0, stream>>>(kb, vT, projb, part, su, stabE);
  // 5. assemble k_sum / ksum_tot
  k_asm_ksum<<<BHN, 256, 0, stream>>>(su, stabE, k_sum, ksum_t);
  // 6. assemble context (bf16) + ctsum
  k_asm_ct<<<BHN, 256, 0, stream>>>(part, vsum, stabE, ct_bf, ctsum);
  // 7. fused query features + attention (writes attn_bf=kb after kb dead)
  k_fq_attn<<<dim3(SEQ / 64, BHN), 256, 0, stream>>>(qb, projb, k_sum, ksum_t, ct_bf, ctsum, attn_bf);
  // 8. output projection (fp32 out, overwrites vT scratch region)
  k_gemm<false><<<gq, 256, 0, stream>>>(attn_bf, wob, d_out, bo, EMB, EMB, EMB, EMB);
}

// Round 11
// 554.203 us; speedup vs baseline: 1.4495x; 1.0118x over previous
//
#include <hip/hip_runtime.h>
#include <hip/hip_bf16.h>
#include <stdint.h>

// Performer (FAVOR+) forward, MI355X/gfx950.
// B=4, N=4096, E=1024, H=16, D=64, M(features)=256.
// bf16 MFMA (16x16x32) everywhere matmul-shaped, fp32 accumulate/epilogues.
// kf never materialized: kf = ratio*(e^-stab * U + eps), U = exp(dd-diag) is
// stab-free; context/k_sum assembled linearly from fused U^T·v and U^T·1.
// R3: k_fk_ctx barrier-free (per-wave sU, direct global frags, vT scratch).
// R4: k_fq_attn operand-swapped feature GEMM; XCD swizzle on k_gemm.
// R5: k_fk_ctx per-token-granule accR strip. MEASURED: 85.5 -> 74 us.
// R6: k_fq_attn spill fix (accC strip). MEASURED: total 578 -> 563 us.
// R7/R8/R9 FAILED (spill); R10 revert confirmed 560.7 us; k_fk_ctx CLOSED.
// R11: QKV GEMMs fused into ONE k_gemm3 (N=3072, concatenated weights,
// shared A=xb): A-panel L2 reuse across 24 col-blocks (was 8x3 launches),
// 2 fewer dispatches, and -- key -- the fused ~103-GFLOP dispatch becomes
// the top dispatch, exposing GEMM counters (VGPR/MfmaUtil/Occ/FETCH/WRITE)
// for the first time. q/k/v become column slices of one [16384][3072]
// buffer (consumer row-stride EMB -> LDQ=3072); attn_bf re-aliased to xb
// (part dead after k_asm_ct). gemm_core untouched.

#define TOKN  16384
#define SEQ   4096
#define EMB   1024
#define LDQ   3072   // fused qkv row stride
#define NHEAD 16
#define HD    64
#define NF    256
#define BHN   64   // batch*heads

static __device__ __forceinline__ constexpr float c1f()  { return 0.35355339059327379f; } // 64^-0.25
static __device__ __forceinline__ constexpr float ratf() { return 0.0625f; }              // 256^-0.5
static __device__ __forceinline__ constexpr float kepsf(){ return 1e-4f; }

typedef unsigned short u16;
typedef unsigned int   u32;
typedef __attribute__((ext_vector_type(8))) short bf16x8;
typedef __attribute__((ext_vector_type(4))) float f32x4;
typedef __attribute__((ext_vector_type(4))) u16   u16x4;

union U8 { bf16x8 v8; u16x4 q[2]; };

__device__ __forceinline__ float bf2f(u16 u) { return __uint_as_float(((u32)u) << 16); }
__device__ __forceinline__ u16 f2bf(float f) {
  u32 u = __float_as_uint(f);
  u += 0x7fffu + ((u >> 16) & 1u);   // RNE
  return (u16)(u >> 16);
}
// order-preserving float<->uint encoding for atomicMax on a float
__device__ __forceinline__ u32 encf(float f) {
  u32 u = __float_as_uint(f);
  return (u & 0x80000000u) ? ~u : (u | 0x80000000u);
}
__device__ __forceinline__ float decf(u32 e) {
  u32 u = (e & 0x80000000u) ? (e & 0x7fffffffu) : ~e;
  return __uint_as_float(u);
}

__device__ __forceinline__ void gl2lds16(const u16* g, void* l) {
  __builtin_amdgcn_global_load_lds(
      (const __attribute__((address_space(1))) u32*)g,
      (__attribute__((address_space(3))) u32*)l, 16, 0, 0);
}

#define ZERO_ACC(acc)                         \
  _Pragma("unroll") for (int _i = 0; _i < 4; _i++) \
  _Pragma("unroll") for (int _j = 0; _j < 4; _j++) acc[_i][_j] = (f32x4)0.0f;

// ---------------------------------------------------------------------------
// m97-style MFMA GEMM core: C[m][n] += sum_k A[m][k]*B[n][k] (both row-major,
// K contiguous). 256 thr = 4 waves; wave tile 64x64 (4x4 of 16x16x32). BK=32.
// ---------------------------------------------------------------------------
template <int BM, int BN>
__device__ __forceinline__ void gemm_core(const u16* __restrict__ Ag, long lda,
                                          const u16* __restrict__ Bg, long ldb,
                                          int K, u16* sA, u16* sB,
                                          f32x4 (&acc)[4][4]) {
  const int tid = threadIdx.x;
  const int w = tid >> 6, l = tid & 63;
  constexpr int WM = BM / 64;
  const int wm = w % WM, wn = w / WM;
  const int lrow = l & 15, lk = (l >> 4) * 8;
  constexpr int AI = (BM * 4) / 256;
  constexpr int BI = (BN * 4) / 256;

  for (int k0 = 0; k0 < K; k0 += 32) {
    __syncthreads();
#pragma unroll
    for (int i = 0; i < AI; i++) {
      int q = i * 256 + tid;
      gl2lds16(Ag + (long)(q >> 2) * lda + k0 + (q & 3) * 8,
               (char*)sA + i * 4096 + w * 1024);
    }
#pragma unroll
    for (int i = 0; i < BI; i++) {
      int q = i * 256 + tid;
      gl2lds16(Bg + (long)(q >> 2) * ldb + k0 + (q & 3) * 8,
               (char*)sB + i * 4096 + w * 1024);
    }
    __syncthreads();
    bf16x8 af[4], bfr[4];
#pragma unroll
    for (int mt = 0; mt < 4; mt++)
      af[mt] = *(const bf16x8*)(sA + ((wm * 64 + mt * 16 + lrow) * 32 + lk));
#pragma unroll
    for (int nt = 0; nt < 4; nt++)
      bfr[nt] = *(const bf16x8*)(sB + ((wn * 64 + nt * 16 + lrow) * 32 + lk));
#pragma unroll
    for (int mt = 0; mt < 4; mt++)
#pragma unroll
      for (int nt = 0; nt < 4; nt++)
        acc[mt][nt] = __builtin_amdgcn_mfma_f32_16x16x32_bf16(af[mt], bfr[nt], acc[mt][nt], 0, 0, 0);
  }
}

// ---------------------------------------------------------------------------
// Big 128x128 GEMM: C = A*B^T + bias. XCD-aware block swizzle.
// ---------------------------------------------------------------------------
template <bool BF16OUT>
__global__ __launch_bounds__(256) void k_gemm(const u16* __restrict__ A, const u16* __restrict__ Bw,
                                              void* __restrict__ Cout, const float* __restrict__ bias,
                                              int K, int lda, int ldb, int ldc) {
  __shared__ __align__(16) u16 sA[128 * 32];
  __shared__ __align__(16) u16 sB[128 * 32];
  const int nbx = gridDim.x;
  const int nwg = nbx * gridDim.y;
  int lin = blockIdx.y * nbx + blockIdx.x;
  if ((nwg & 7) == 0) {                    // bijective XCD swizzle (nwg%8==0)
    int per = nwg >> 3;
    lin = (lin & 7) * per + (lin >> 3);
  }
  const int m0 = (lin / nbx) * 128, n0 = (lin % nbx) * 128;
  f32x4 acc[4][4]; ZERO_ACC(acc);
  gemm_core<128, 128>(A + (long)m0 * lda, lda, Bw + (long)n0 * ldb, ldb, K, sA, sB, acc);
  const int l = threadIdx.x & 63, w = threadIdx.x >> 6;
  const int wm = w & 1, wn = w >> 1, lr4 = (l >> 4) * 4, lc = l & 15;
#pragma unroll
  for (int nt = 0; nt < 4; nt++) {
    int gcol = n0 + wn * 64 + nt * 16 + lc;
    float bia = bias[gcol];
#pragma unroll
    for (int mt = 0; mt < 4; mt++)
#pragma unroll
      for (int r = 0; r < 4; r++) {
        int grow = m0 + wm * 64 + mt * 16 + lr4 + r;
        float v = acc[mt][nt][r] + bia;
        if (BF16OUT) ((u16*)Cout)[(long)grow * ldc + gcol] = f2bf(v);
        else         ((float*)Cout)[(long)grow * ldc + gcol] = v;
      }
  }
}

// ---------------------------------------------------------------------------
// R11: fused QKV GEMM. C[16384][3072] = xb * [Wq;Wk;Wv]^T + [bq|bk|bv].
// Weight rows 0..1023 = Wq, 1024..2047 = Wk, 2048..3071 = Wv. Blocks never
// straddle a 1024-col boundary (1024 % 128 == 0) -> bias segment per block.
// ---------------------------------------------------------------------------
__global__ __launch_bounds__(256) void k_gemm3(const u16* __restrict__ A, const u16* __restrict__ Bw,
                                               u16* __restrict__ Cout,
                                               const float* __restrict__ b0, const float* __restrict__ b1,
                                               const float* __restrict__ b2,
                                               int K, int lda, int ldb, int ldc) {
  __shared__ __align__(16) u16 sA[128 * 32];
  __shared__ __align__(16) u16 sB[128 * 32];
  const int nbx = gridDim.x;
  const int nwg = nbx * gridDim.y;
  int lin = blockIdx.y * nbx + blockIdx.x;
  if ((nwg & 7) == 0) {                    // bijective XCD swizzle (nwg%8==0)
    int per = nwg >> 3;
    lin = (lin & 7) * per + (lin >> 3);
  }
  const int m0 = (lin / nbx) * 128, n0 = (lin % nbx) * 128;
  f32x4 acc[4][4]; ZERO_ACC(acc);
  gemm_core<128, 128>(A + (long)m0 * lda, lda, Bw + (long)n0 * ldb, ldb, K, sA, sB, acc);
  const int l = threadIdx.x & 63, w = threadIdx.x >> 6;
  const int wm = w & 1, wn = w >> 1, lr4 = (l >> 4) * 4, lc = l & 15;
  const int seg = n0 >> 10;
  const float* bias = seg == 0 ? b0 : (seg == 1 ? b1 : b2);
#pragma unroll
  for (int nt = 0; nt < 4; nt++) {
    int gcol = n0 + wn * 64 + nt * 16 + lc;
    float bia = bias[gcol & 1023];
#pragma unroll
    for (int mt = 0; mt < 4; mt++)
#pragma unroll
      for (int r = 0; r < 4; r++) {
        int grow = m0 + wm * 64 + mt * 16 + lr4 + r;
        Cout[(long)grow * ldc + gcol] = f2bf(acc[mt][nt][r] + bia);
      }
  }
}

// ---------------------------------------------------------------------------
// v transpose: v slice of qkv [tok][LDQ] -> vT[bh][d][n] (bf16), plus vsum.
// ---------------------------------------------------------------------------
__global__ __launch_bounds__(256) void k_vT(const u16* __restrict__ vb, u16* __restrict__ vT,
                                            float* __restrict__ vsum) {
  __shared__ u16 t[64][72];   // 72 stride: 8B-aligned rows, conflict-benign
  const int bh = blockIdx.y, n0 = blockIdx.x * 64, b = bh >> 4, h = bh & 15;
  const int tid = threadIdx.x;
#pragma unroll
  for (int i = 0; i < 2; i++) {
    int idx = i * 256 + tid, row = idx >> 3, c8 = idx & 7;
    U8 u;
    u.v8 = *(const bf16x8*)&vb[((long)(b * SEQ) + n0 + row) * LDQ + h * HD + c8 * 8];
    *(u16x4*)&t[row][c8 * 8]     = u.q[0];
    *(u16x4*)&t[row][c8 * 8 + 4] = u.q[1];
  }
  __syncthreads();
  const int nq = tid & 15, dh = tid >> 4;
#pragma unroll
  for (int i = 0; i < 4; i++) {
    int d = i * 16 + dh;
    u16x4 pk; float s = 0.f;
#pragma unroll
    for (int j = 0; j < 4; j++) { u16 v = t[nq * 4 + j][d]; pk[j] = v; s += bf2f(v); }
    *(u16x4*)&vT[((long)bh * HD + d) * SEQ + n0 + nq * 4] = pk;
    s += __shfl_xor(s, 1); s += __shfl_xor(s, 2);
    s += __shfl_xor(s, 4); s += __shfl_xor(s, 8);
    if (nq == 0) atomicAdd(&vsum[bh * HD + d], s);
  }
}

// ---------------------------------------------------------------------------
// Fused key features + context partials, BARRIER-FREE. (CLOSED at 74 us.)
// kb is the k slice of qkv (row stride LDQ).
// ---------------------------------------------------------------------------
__global__ __launch_bounds__(256, 2) void k_fk_ctx(const u16* __restrict__ kb, const u16* __restrict__ vT,
                                                   const u16* __restrict__ projb, u16* __restrict__ part,
                                                   float* __restrict__ su, u32* __restrict__ stabEnc) {
  __shared__ __align__(16) u16 sU[4][64 * 64];   // per-wave 8KB regions
  const int ck = blockIdx.x, bh = blockIdx.y, b = bh >> 4, h = bh & 15;
  const int tid = threadIdx.x, w = tid >> 6, l = tid & 63;
  const int c = l & 15, g = l >> 4;
  u16* sUw = &sU[w][0];
  const int sw = c & 7;

  // proj B-fragments in registers: features w*64+nt*16+c, k = k0*32+g*8+j
  bf16x8 pf[4][2];
#pragma unroll
  for (int nt = 0; nt < 4; nt++)
#pragma unroll
    for (int k0 = 0; k0 < 2; k0++)
      pf[nt][k0] = *(const bf16x8*)&projb[(w * 64 + nt * 16 + c) * 64 + k0 * 32 + g * 8];

  f32x4 acc2[4][4]; ZERO_ACC(acc2);   // ctx: rows=features(wave-local), cols=d
  float suv[4] = {0.f, 0.f, 0.f, 0.f};
  float amax = -1e30f;                // max raw acc; stab = c1*amax (monotone)
  const long tok0 = (long)b * SEQ + ck * 256;

  for (int s = 0; s < 4; s++) {
    const long t0 = tok0 + s * 64;
    // A-fragments direct from global: token = mt*16+c, k(d) = k0*32+g*8+j
    bf16x8 af[4][2];
#pragma unroll
    for (int mt = 0; mt < 4; mt++)
#pragma unroll
      for (int k0 = 0; k0 < 2; k0++)
        af[mt][k0] = *(const bf16x8*)&kb[(t0 + mt * 16 + c) * LDQ + h * HD + k0 * 32 + g * 8];
    // hoist vT B-frags for the ctx GEMM: HBM/L3 latency hides under the
    // feature GEMM + epilogue below.
    bf16x8 vf[2][4];
#pragma unroll
    for (int k0 = 0; k0 < 2; k0++)
#pragma unroll
      for (int nt = 0; nt < 4; nt++)
        vf[k0][nt] = *(const bf16x8*)&vT[((long)bh * HD + nt * 16 + c) * SEQ +
                                         ck * 256 + s * 64 + k0 * 32 + g * 8];

    // per-token-granule mt: diag + one 16-row strip of the feature GEMM +
    // epilogue, with accR recycled (peak acc pressure 64+16 not 64+64).
#pragma unroll
    for (int mt = 0; mt < 4; mt++) {
      float ss = 0.f;
#pragma unroll
      for (int k0 = 0; k0 < 2; k0++)
#pragma unroll
        for (int j = 0; j < 8; j++) {
          float v = bf2f((u16)af[mt][k0][j]);
          ss += v * v;
        }
      ss += __shfl_xor(ss, 16);
      ss += __shfl_xor(ss, 32);
      const float dgrow = ss * 0.0625f;   // diag of token mt*16+c
      f32x4 accR[4];
#pragma unroll
      for (int nt = 0; nt < 4; nt++) accR[nt] = (f32x4)0.0f;
#pragma unroll
      for (int k0 = 0; k0 < 2; k0++)
#pragma unroll
        for (int nt = 0; nt < 4; nt++)
          accR[nt] = __builtin_amdgcn_mfma_f32_16x16x32_bf16(af[mt][k0], pf[nt][k0], accR[nt], 0, 0, 0);
      // epilogue: U = exp(c1*acc - diag) -> per-wave sU (swizzled), su, stab
      float dg[4];
#pragma unroll
      for (int r = 0; r < 4; r++) dg[r] = __shfl(dgrow, g * 4 + r);
#pragma unroll
      for (int nt = 0; nt < 4; nt++) {
        u16x4 pk;
#pragma unroll
        for (int r = 0; r < 4; r++) {
          float a = accR[nt][r];
          amax = fmaxf(amax, a);
          float U = __expf(fmaf(a, c1f(), -dg[r]));
          pk[r] = f2bf(U);
          suv[nt] += U;
        }
        // write tokens granule G=mt*4+g (pair P=mt*2+(g>>1), b=g&1), row nt*16+c
        *(u16x4*)&sUw[(nt * 16 + c) * 64 + (((mt * 2 + (g >> 1)) ^ sw) * 2 + (g & 1)) * 4] = pk;
      }
    }
    // ctx GEMM: acc2[m][d] += sum_n U^T[m][n] * vT[d][n]  (intra-wave sU reads)
#pragma unroll
    for (int k0 = 0; k0 < 2; k0++) {
      bf16x8 uf[4];
#pragma unroll
      for (int mt = 0; mt < 4; mt++)
        uf[mt] = *(const bf16x8*)&sUw[(mt * 16 + c) * 64 + ((k0 * 4 + g) ^ sw) * 8];
#pragma unroll
      for (int mt = 0; mt < 4; mt++)
#pragma unroll
        for (int nt = 0; nt < 4; nt++)
          acc2[mt][nt] = __builtin_amdgcn_mfma_f32_16x16x32_bf16(uf[mt], vf[k0][nt], acc2[mt][nt], 0, 0, 0);
    }
  }
  // store ctx partials bf16: part[z][m][d]
  const long zp = (long)(bh * 16 + ck);
#pragma unroll
  for (int mt = 0; mt < 4; mt++)
#pragma unroll
    for (int nt = 0; nt < 4; nt++)
#pragma unroll
      for (int r = 0; r < 4; r++) {
        int m = w * 64 + mt * 16 + g * 4 + r;
        int d = nt * 16 + c;
        part[(zp * NF + m) * HD + d] = f2bf(acc2[mt][nt][r]);
      }
  // su atomic (reduce over lane groups sharing c)
#pragma unroll
  for (int nt = 0; nt < 4; nt++) {
    float v = suv[nt];
    v += __shfl_xor(v, 16);
    v += __shfl_xor(v, 32);
    if (l < 16) atomicAdd(&su[bh * NF + w * 64 + nt * 16 + l], v);
  }
  for (int o = 32; o; o >>= 1) amax = fmaxf(amax, __shfl_xor(amax, o));
  if (l == 0) atomicMax(stabEnc, encf(c1f() * amax));
}

// ---------------------------------------------------------------------------
// Fused query features + attention. One block per (64-token tile, bh).
// qb is the q slice of qkv (row stride LDQ); attn_bf separate (stride EMB).
// ---------------------------------------------------------------------------
__global__ __launch_bounds__(256, 4) void k_fq_attn(const u16* __restrict__ qb, const u16* __restrict__ projb,
                                                    const float* __restrict__ k_sum, const float* __restrict__ ksum_tot,
                                                    const u16* __restrict__ ct_bf, const float* __restrict__ ctsum,
                                                    u16* __restrict__ attn_bf) {
  __shared__ __align__(16) u16 sUq[64 * 256];    // Uq [token][m], 16B-granule swizzled
  __shared__ float redmax[4][64];
  __shared__ float redsum[4][64];
  const int bh = blockIdx.y, b = bh >> 4, h = bh & 15;
  const long t0 = (long)b * SEQ + blockIdx.x * 64;
  const int tid = threadIdx.x, w = tid >> 6, l = tid & 63;
  const int lrow = l & 15, lk = (l >> 4) * 8, lr4 = (l >> 4) * 4, lc = l & 15;

  // A-frags: proj rows = features w*64+mt*16+lrow, k = k0*32+lk+j
  bf16x8 pf[4][2];
#pragma unroll
  for (int mt = 0; mt < 4; mt++)
#pragma unroll
    for (int k0 = 0; k0 < 2; k0++)
      pf[mt][k0] = *(const bf16x8*)&projb[(w * 64 + mt * 16 + lrow) * 64 + k0 * 32 + lk];
  // B-frags: q rows = tokens nt*16+lrow (direct from global, fk_ctx pattern).
  bf16x8 af[4][2];
#pragma unroll
  for (int nt = 0; nt < 4; nt++)
#pragma unroll
    for (int k0 = 0; k0 < 2; k0++)
      af[nt][k0] = *(const bf16x8*)&qb[(t0 + nt * 16 + lrow) * LDQ + h * HD + k0 * 32 + lk];

  // inline diag per token: each lane ends with diag of its OWN token nt*16+lc
  float dgq[4];
#pragma unroll
  for (int nt = 0; nt < 4; nt++) {
    float ss = 0.f;
#pragma unroll
    for (int k0 = 0; k0 < 2; k0++)
#pragma unroll
      for (int j = 0; j < 8; j++) {
        float v = bf2f((u16)af[nt][k0][j]);
        ss += v * v;
      }
    ss += __shfl_xor(ss, 16);
    ss += __shfl_xor(ss, 32);
    dgq[nt] = ss * 0.0625f;
  }

  // k_sum for this lane's 16 features (mt, lr4+r)
  f32x4 ksr[4];
#pragma unroll
  for (int mt = 0; mt < 4; mt++)
    ksr[mt] = *(const f32x4*)&k_sum[(long)bh * NF + w * 64 + mt * 16 + lr4];

  // per-token-granule nt: 16-col strip of the feature GEMM (accC recycled)
  // + epilogue: U -> sUq (u16x4 along features, swizzled), per-token max,
  // sum(U*ksum) partials.
#pragma unroll
  for (int nt = 0; nt < 4; nt++) {
    f32x4 accC[4];
#pragma unroll
    for (int mt = 0; mt < 4; mt++) accC[mt] = (f32x4)0.0f;
#pragma unroll
    for (int k0 = 0; k0 < 2; k0++)
#pragma unroll
      for (int mt = 0; mt < 4; mt++)
        accC[mt] = __builtin_amdgcn_mfma_f32_16x16x32_bf16(pf[mt][k0], af[nt][k0], accC[mt], 0, 0, 0);

    const int tok = nt * 16 + lc;
    const int trow = tok * NF, tsw = tok & 7;
    float vmax = -1e30f, s = 0.f;
#pragma unroll
    for (int mt = 0; mt < 4; mt++) {
      const int fb = w * 64 + mt * 16 + lr4;   // multiple of 4
      u16x4 pk;
#pragma unroll
      for (int r = 0; r < 4; r++) {
        float dd = c1f() * accC[mt][r];
        vmax = fmaxf(vmax, dd);
        float U = __expf(dd - dgq[nt]);
        pk[r] = f2bf(U);
        s += U * ksr[mt][r];
      }
      *(u16x4*)&sUq[trow + (((fb >> 3) ^ tsw) << 3) + (fb & 7)] = pk;
    }
    vmax = fmaxf(vmax, __shfl_xor(vmax, 16));
    vmax = fmaxf(vmax, __shfl_xor(vmax, 32));
    s += __shfl_xor(s, 16);
    s += __shfl_xor(s, 32);
    if (l < 16) { redmax[w][nt * 16 + l] = vmax; redsum[w][nt * 16 + l] = s; }
  }
  __syncthreads();
  // attention GEMM: wave w owns d in [w*16, w*16+16); K = 256 features
  f32x4 acc2[4];
#pragma unroll
  for (int mt = 0; mt < 4; mt++) acc2[mt] = (f32x4)0.0f;
#pragma unroll
  for (int kk = 0; kk < 8; kk++) {
    bf16x8 bfr = *(const bf16x8*)&ct_bf[((long)bh * HD + w * 16 + lrow) * NF + kk * 32 + lk];
#pragma unroll
    for (int mt = 0; mt < 4; mt++) {
      int row = mt * 16 + lrow;
      bf16x8 a2 = *(const bf16x8*)&sUq[row * NF + (((kk * 4 + (l >> 4)) ^ (row & 7)) * 8)];
      acc2[mt] = __builtin_amdgcn_mfma_f32_16x16x32_bf16(a2, bfr, acc2[mt], 0, 0, 0);
    }
  }
  // epilogue: alpha/beta per row, write bf16 attn in [B,N,E]
  const float kst = ksum_tot[bh];
  const float cts = ctsum[(long)bh * HD + w * 16 + lc];
#pragma unroll
  for (int mt = 0; mt < 4; mt++)
#pragma unroll
    for (int r = 0; r < 4; r++) {
      int row = mt * 16 + lr4 + r;
      float rs = fmaxf(fmaxf(redmax[0][row], redmax[1][row]),
                       fmaxf(redmax[2][row], redmax[3][row]));
      float S1 = redsum[0][row] + redsum[1][row] + redsum[2][row] + redsum[3][row];
      float ers = __expf(-rs);
      float di = 1.0f / (ratf() * (ers * S1 + kepsf() * kst));
      float a_ = di * ratf() * ers;
      float b_ = di * ratf() * kepsf();
      float ov = a_ * acc2[mt][r] + b_ * cts;
      attn_bf[(t0 + row) * EMB + h * HD + w * 16 + lc] = f2bf(ov);
    }
}

// --------------------------- glue kernels ----------------------------------
__global__ void k_cvt(const float* __restrict__ s, u16* __restrict__ d, long n4) {
  long i = (long)blockIdx.x * blockDim.x + threadIdx.x;
  if (i >= n4) return;
  float4 v = ((const float4*)s)[i];
  u16x4 o = { f2bf(v.x), f2bf(v.y), f2bf(v.z), f2bf(v.w) };
  ((u16x4*)d)[i] = o;
}

__global__ void k_init(float* su, float* vsum, u32* stabEnc) {
  int i = blockIdx.x * 256 + threadIdx.x;
  if (i < BHN * NF) su[i] = 0.f;
  if (i < BHN * HD) vsum[i] = 0.f;
  if (i == 0) *stabEnc = 0u;
}

// k_sum[m] = ratio*(e^-stab*su[m] + eps*SEQ); ksum_tot = sum_m k_sum
__global__ __launch_bounds__(256) void k_asm_ksum(const float* __restrict__ su, const u32* __restrict__ stabEnc,
                                                  float* __restrict__ k_sum, float* __restrict__ ksum_tot) {
  __shared__ float red[256];
  int z = blockIdx.x, m = threadIdx.x;
  float es = __expf(-decf(*stabEnc));
  float v = ratf() * (es * su[(long)z * NF + m] + kepsf() * (float)SEQ);
  k_sum[(long)z * NF + m] = v;
  red[m] = v;
  __syncthreads();
  for (int s = 128; s > 0; s >>= 1) {
    if (m < s) red[m] += red[m + s];
    __syncthreads();
  }
  if (m == 0) ksum_tot[z] = red[0];
}

// ct[d][m] = ratio*(e^-stab*sum_ck part[m][d] + eps*vsum[d]) -> bf16; ctsum[d]
__global__ __launch_bounds__(256) void k_asm_ct(const u16* __restrict__ part, const float* __restrict__ vsum,
                                                const u32* __restrict__ stabEnc, u16* __restrict__ ct_bf,
                                                float* __restrict__ ctsum) {
  __shared__ float red[4][64];
  const int z = blockIdx.x, tid = threadIdx.x;
  const int w = tid >> 6, l = tid & 63;
  float es = __expf(-decf(*stabEnc));
  float vs = vsum[(long)z * HD + l];
  float csum = 0.f;
  for (int m = w; m < NF; m += 4) {
    float a = 0.f;
#pragma unroll
    for (int ck = 0; ck < 16; ck++)
      a += bf2f(part[((long)(z * 16 + ck) * NF + m) * HD + l]);
    float cv = ratf() * (es * a + kepsf() * vs);
    ct_bf[((long)z * HD + l) * NF + m] = f2bf(cv);
    csum += cv;
  }
  red[w][l] = csum;
  __syncthreads();
  if (tid < 64)
    ctsum[(long)z * HD + tid] = red[0][tid] + red[1][tid] + red[2][tid] + red[3][tid];
}

// ---------------------------------------------------------------------------
extern "C" void kernel_launch(void* const* d_in, const int* in_sizes, int n_in,
                              void* d_out, int out_size, void* d_ws, size_t ws_size,
                              hipStream_t stream) {
  const float* x    = (const float*)d_in[0];
  const float* Wq   = (const float*)d_in[1];
  const float* bq   = (const float*)d_in[2];
  const float* Wk   = (const float*)d_in[3];
  const float* bk   = (const float*)d_in[4];
  const float* Wv   = (const float*)d_in[5];
  const float* bv   = (const float*)d_in[6];
  const float* Wo   = (const float*)d_in[7];
  const float* bo   = (const float*)d_in[8];
  const float* proj = (const float*)d_in[9];

  char* base = (char*)d_ws;
  size_t off = 0;
  auto alloc = [&](size_t bytes) {
    off = (off + 255) & ~(size_t)255;
    char* r = base + off;
    off += bytes;
    return r;
  };
  // ~145 MB total (was ~153): qkv fused, attn_bf aliased to xb.
  u16*  xb     = (u16*)alloc((size_t)TOKN * EMB * 2);   // 33.5 MB; -> part -> attn_bf
  u16*  wqkv   = (u16*)alloc((size_t)3 * EMB * EMB * 2);// 6 MB [Wq;Wk;Wv]
  u16*  wob    = (u16*)alloc((size_t)EMB * EMB * 2);
  u16*  projb  = (u16*)alloc((size_t)NF * HD * 2);
  u16*  qkv    = (u16*)alloc((size_t)TOKN * LDQ * 2);   // 100.7 MB fused output
  float* su    = (float*)alloc((size_t)BHN * NF * 4);
  float* k_sum = (float*)alloc((size_t)BHN * NF * 4);
  float* ksum_t= (float*)alloc((size_t)BHN * 4);
  float* vsum  = (float*)alloc((size_t)BHN * HD * 4);
  float* ctsum = (float*)alloc((size_t)BHN * HD * 4);
  u32*  stabE  = (u32*)alloc(256);
  u16*  ct_bf  = (u16*)alloc((size_t)BHN * HD * NF * 2); // 2 MB
  u16*  qb     = qkv;              // column slices, row stride LDQ
  u16*  kb     = qkv + EMB;
  u16*  vb     = qkv + 2 * EMB;
  u16*  part   = xb;               // xb dead after QKV GEMM
  u16*  attn_bf= xb;               // part dead after k_asm_ct (step 6)
  u16*  vT     = (u16*)d_out;      // d_out scratch until final GEMM

  // 0. init atomic accumulators
  k_init<<<64, 256, 0, stream>>>(su, vsum, stabE);
  // 1. fp32 -> bf16
  k_cvt<<<(TOKN * EMB / 4 + 255) / 256, 256, 0, stream>>>(x, xb, (long)TOKN * EMB / 4);
  k_cvt<<<(EMB * EMB / 4 + 255) / 256, 256, 0, stream>>>(Wq, wqkv, (long)EMB * EMB / 4);
  k_cvt<<<(EMB * EMB / 4 + 255) / 256, 256, 0, stream>>>(Wk, wqkv + (size_t)EMB * EMB, (long)EMB * EMB / 4);
  k_cvt<<<(EMB * EMB / 4 + 255) / 256, 256, 0, stream>>>(Wv, wqkv + (size_t)2 * EMB * EMB, (long)EMB * EMB / 4);
  k_cvt<<<(EMB * EMB / 4 + 255) / 256, 256, 0, stream>>>(Wo, wob, (long)EMB * EMB / 4);
  k_cvt<<<(NF * HD / 4 + 255) / 256, 256, 0, stream>>>(proj, projb, (long)NF * HD / 4);
  // 2. fused QKV projection: [16384][3072] = xb * [Wq;Wk;Wv]^T + bias
  k_gemm3<<<dim3(LDQ / 128, TOKN / 128), 256, 0, stream>>>(xb, wqkv, qkv, bq, bk, bv,
                                                           EMB, EMB, EMB, LDQ);
  // 3. v transpose into d_out scratch + vsum
  k_vT<<<dim3(SEQ / 64, BHN), 256, 0, stream>>>(vb, vT, vsum);
  // 4. fused key features + context partials (writes part=xb after xb dead)
  k_fk_ctx<<<dim3(16, BHN), 256, 0, stream>>>(kb, vT, projb, part, su, stabE);
  // 5. assemble k_sum / ksum_tot
  k_asm_ksum<<<BHN, 256, 0, stream>>>(su, stabE, k_sum, ksum_t);
  // 6. assemble context (bf16) + ctsum
  k_asm_ct<<<BHN, 256, 0, stream>>>(part, vsum, stabE, ct_bf, ctsum);
  // 7. fused query features + attention (writes attn_bf=xb after part dead)
  k_fq_attn<<<dim3(SEQ / 64, BHN), 256, 0, stream>>>(qb, projb, k_sum, ksum_t, ct_bf, ctsum, attn_bf);
  // 8. output projection (fp32 out, overwrites vT scratch region)
  k_gemm<false><<<dim3(EMB / 128, TOKN / 128), 256, 0, stream>>>(attn_bf, wob, d_out, bo, EMB, EMB, EMB, EMB);
}

// Round 12
// 513.010 us; speedup vs baseline: 1.5659x; 1.0803x over previous
//
#include <hip/hip_runtime.h>
#include <hip/hip_bf16.h>
#include <stdint.h>

// Performer (FAVOR+) forward, MI355X/gfx950.
// B=4, N=4096, E=1024, H=16, D=64, M(features)=256.
// bf16 MFMA (16x16x32) everywhere matmul-shaped, fp32 accumulate/epilogues.
// kf never materialized: kf = ratio*(e^-stab * U + eps), U = exp(dd-diag) is
// stab-free; context/k_sum assembled linearly from fused U^T·v and U^T·1.
// R3: k_fk_ctx barrier-free. R4: fq_attn operand-swap; XCD swizzle.
// R5: fk_ctx accR strip (85.5->74us). R6: fq_attn spill fix (578->563us).
// R7/R8/R9 FAILED (spill). R10 revert = 560.7us; fk_ctx CLOSED.
// R11: QKV fused into k_gemm3 (N=3072). MEASURED 554.2us; k_gemm3 = 155us,
// 665 TF, VGPR 80+64 AGPR = 144 unified -> 2 waves/SIMD bucket-locked;
// bank-conflict 12.6M (m252 signature: fixing alone = null at 2-phase);
// critical path = per-K-step vmcnt(0)+barrier drain (m233: ~72% of 2-phase).
// R12: BK=64 in gemm_core -> HALF the barrier-drain events, 32 MFMA/barrier
// (AITER ratio). Frags recycled per K-half (register demand unchanged, no
// spill exposure). LDS 16->32KB. Granule-XOR swizzle both-sides (linear LDS
// dest + inverse-permuted global source + XOR'd ds_read; rule #21, same
// pattern as sUq/sU) keeps ds_read_b128 conflict-free at the 128-B row
// stride. Bit-identical numerics. Both k_gemm3 and k_gemm inherit.

#define TOKN  16384
#define SEQ   4096
#define EMB   1024
#define LDQ   3072   // fused qkv row stride
#define NHEAD 16
#define HD    64
#define NF    256
#define BHN   64   // batch*heads

static __device__ __forceinline__ constexpr float c1f()  { return 0.35355339059327379f; } // 64^-0.25
static __device__ __forceinline__ constexpr float ratf() { return 0.0625f; }              // 256^-0.5
static __device__ __forceinline__ constexpr float kepsf(){ return 1e-4f; }

typedef unsigned short u16;
typedef unsigned int   u32;
typedef __attribute__((ext_vector_type(8))) short bf16x8;
typedef __attribute__((ext_vector_type(4))) float f32x4;
typedef __attribute__((ext_vector_type(4))) u16   u16x4;

union U8 { bf16x8 v8; u16x4 q[2]; };

__device__ __forceinline__ float bf2f(u16 u) { return __uint_as_float(((u32)u) << 16); }
__device__ __forceinline__ u16 f2bf(float f) {
  u32 u = __float_as_uint(f);
  u += 0x7fffu + ((u >> 16) & 1u);   // RNE
  return (u16)(u >> 16);
}
// order-preserving float<->uint encoding for atomicMax on a float
__device__ __forceinline__ u32 encf(float f) {
  u32 u = __float_as_uint(f);
  return (u & 0x80000000u) ? ~u : (u | 0x80000000u);
}
__device__ __forceinline__ float decf(u32 e) {
  u32 u = (e & 0x80000000u) ? (e & 0x7fffffffu) : ~e;
  return __uint_as_float(u);
}

__device__ __forceinline__ void gl2lds16(const u16* g, void* l) {
  __builtin_amdgcn_global_load_lds(
      (const __attribute__((address_space(1))) u32*)g,
      (__attribute__((address_space(3))) u32*)l, 16, 0, 0);
}

#define ZERO_ACC(acc)                         \
  _Pragma("unroll") for (int _i = 0; _i < 4; _i++) \
  _Pragma("unroll") for (int _j = 0; _j < 4; _j++) acc[_i][_j] = (f32x4)0.0f;

// ---------------------------------------------------------------------------
// MFMA GEMM core, R12: BK=64, 2 K-halves per barrier pair (32 MFMA/barrier).
// C[m][n] += sum_k A[m][k]*B[n][k] (both row-major, K contiguous).
// 256 thr = 4 waves; wave tile 64x64 (4x4 of 16x16x32).
// LDS rows are 128 B; staging pre-permutes the global source granule
// (part ^ (row&7)) so the linear global_load_lds dest equals the swizzled
// layout; ds_read XORs the same involution -> conflict-free b128 reads.
// ---------------------------------------------------------------------------
template <int BM, int BN>
__device__ __forceinline__ void gemm_core(const u16* __restrict__ Ag, long lda,
                                          const u16* __restrict__ Bg, long ldb,
                                          int K, u16* sA, u16* sB,
                                          f32x4 (&acc)[4][4]) {
  const int tid = threadIdx.x;
  const int w = tid >> 6, l = tid & 63;
  constexpr int WM = BM / 64;
  const int wm = w % WM, wn = w / WM;
  const int lrow = l & 15, g4 = l >> 4;    // g4 = 16B-granule index in K-half
  constexpr int AI = (BM * 8) / 256;       // 16B chunks per tile / 256 thr
  constexpr int BI = (BN * 8) / 256;

  for (int k0 = 0; k0 < K; k0 += 64) {
    __syncthreads();
#pragma unroll
    for (int i = 0; i < AI; i++) {
      int q = i * 256 + tid;
      int row = q >> 3, part = (q & 7) ^ (row & 7);   // inverse-swz source
      gl2lds16(Ag + (long)row * lda + k0 + part * 8,
               (char*)sA + i * 4096 + w * 1024);
    }
#pragma unroll
    for (int i = 0; i < BI; i++) {
      int q = i * 256 + tid;
      int row = q >> 3, part = (q & 7) ^ (row & 7);
      gl2lds16(Bg + (long)row * ldb + k0 + part * 8,
               (char*)sB + i * 4096 + w * 1024);
    }
    __syncthreads();
#pragma unroll
    for (int kk = 0; kk < 2; kk++) {
      bf16x8 af[4], bfr[4];
#pragma unroll
      for (int mt = 0; mt < 4; mt++) {
        int row = wm * 64 + mt * 16 + lrow;
        af[mt] = *(const bf16x8*)(sA + row * 64 + (((kk * 4 + g4) ^ (row & 7)) * 8));
      }
#pragma unroll
      for (int nt = 0; nt < 4; nt++) {
        int row = wn * 64 + nt * 16 + lrow;
        bfr[nt] = *(const bf16x8*)(sB + row * 64 + (((kk * 4 + g4) ^ (row & 7)) * 8));
      }
#pragma unroll
      for (int mt = 0; mt < 4; mt++)
#pragma unroll
        for (int nt = 0; nt < 4; nt++)
          acc[mt][nt] = __builtin_amdgcn_mfma_f32_16x16x32_bf16(af[mt], bfr[nt], acc[mt][nt], 0, 0, 0);
    }
  }
}

// ---------------------------------------------------------------------------
// Big 128x128 GEMM: C = A*B^T + bias. XCD-aware block swizzle.
// ---------------------------------------------------------------------------
template <bool BF16OUT>
__global__ __launch_bounds__(256) void k_gemm(const u16* __restrict__ A, const u16* __restrict__ Bw,
                                              void* __restrict__ Cout, const float* __restrict__ bias,
                                              int K, int lda, int ldb, int ldc) {
  __shared__ __align__(16) u16 sA[128 * 64];
  __shared__ __align__(16) u16 sB[128 * 64];
  const int nbx = gridDim.x;
  const int nwg = nbx * gridDim.y;
  int lin = blockIdx.y * nbx + blockIdx.x;
  if ((nwg & 7) == 0) {                    // bijective XCD swizzle (nwg%8==0)
    int per = nwg >> 3;
    lin = (lin & 7) * per + (lin >> 3);
  }
  const int m0 = (lin / nbx) * 128, n0 = (lin % nbx) * 128;
  f32x4 acc[4][4]; ZERO_ACC(acc);
  gemm_core<128, 128>(A + (long)m0 * lda, lda, Bw + (long)n0 * ldb, ldb, K, sA, sB, acc);
  const int l = threadIdx.x & 63, w = threadIdx.x >> 6;
  const int wm = w & 1, wn = w >> 1, lr4 = (l >> 4) * 4, lc = l & 15;
#pragma unroll
  for (int nt = 0; nt < 4; nt++) {
    int gcol = n0 + wn * 64 + nt * 16 + lc;
    float bia = bias[gcol];
#pragma unroll
    for (int mt = 0; mt < 4; mt++)
#pragma unroll
      for (int r = 0; r < 4; r++) {
        int grow = m0 + wm * 64 + mt * 16 + lr4 + r;
        float v = acc[mt][nt][r] + bia;
        if (BF16OUT) ((u16*)Cout)[(long)grow * ldc + gcol] = f2bf(v);
        else         ((float*)Cout)[(long)grow * ldc + gcol] = v;
      }
  }
}

// ---------------------------------------------------------------------------
// R11: fused QKV GEMM. C[16384][3072] = xb * [Wq;Wk;Wv]^T + [bq|bk|bv].
// Weight rows 0..1023 = Wq, 1024..2047 = Wk, 2048..3071 = Wv. Blocks never
// straddle a 1024-col boundary (1024 % 128 == 0) -> bias segment per block.
// ---------------------------------------------------------------------------
__global__ __launch_bounds__(256) void k_gemm3(const u16* __restrict__ A, const u16* __restrict__ Bw,
                                               u16* __restrict__ Cout,
                                               const float* __restrict__ b0, const float* __restrict__ b1,
                                               const float* __restrict__ b2,
                                               int K, int lda, int ldb, int ldc) {
  __shared__ __align__(16) u16 sA[128 * 64];
  __shared__ __align__(16) u16 sB[128 * 64];
  const int nbx = gridDim.x;
  const int nwg = nbx * gridDim.y;
  int lin = blockIdx.y * nbx + blockIdx.x;
  if ((nwg & 7) == 0) {                    // bijective XCD swizzle (nwg%8==0)
    int per = nwg >> 3;
    lin = (lin & 7) * per + (lin >> 3);
  }
  const int m0 = (lin / nbx) * 128, n0 = (lin % nbx) * 128;
  f32x4 acc[4][4]; ZERO_ACC(acc);
  gemm_core<128, 128>(A + (long)m0 * lda, lda, Bw + (long)n0 * ldb, ldb, K, sA, sB, acc);
  const int l = threadIdx.x & 63, w = threadIdx.x >> 6;
  const int wm = w & 1, wn = w >> 1, lr4 = (l >> 4) * 4, lc = l & 15;
  const int seg = n0 >> 10;
  const float* bias = seg == 0 ? b0 : (seg == 1 ? b1 : b2);
#pragma unroll
  for (int nt = 0; nt < 4; nt++) {
    int gcol = n0 + wn * 64 + nt * 16 + lc;
    float bia = bias[gcol & 1023];
#pragma unroll
    for (int mt = 0; mt < 4; mt++)
#pragma unroll
      for (int r = 0; r < 4; r++) {
        int grow = m0 + wm * 64 + mt * 16 + lr4 + r;
        Cout[(long)grow * ldc + gcol] = f2bf(acc[mt][nt][r] + bia);
      }
  }
}

// ---------------------------------------------------------------------------
// v transpose: v slice of qkv [tok][LDQ] -> vT[bh][d][n] (bf16), plus vsum.
// ---------------------------------------------------------------------------
__global__ __launch_bounds__(256) void k_vT(const u16* __restrict__ vb, u16* __restrict__ vT,
                                            float* __restrict__ vsum) {
  __shared__ u16 t[64][72];   // 72 stride: 8B-aligned rows, conflict-benign
  const int bh = blockIdx.y, n0 = blockIdx.x * 64, b = bh >> 4, h = bh & 15;
  const int tid = threadIdx.x;
#pragma unroll
  for (int i = 0; i < 2; i++) {
    int idx = i * 256 + tid, row = idx >> 3, c8 = idx & 7;
    U8 u;
    u.v8 = *(const bf16x8*)&vb[((long)(b * SEQ) + n0 + row) * LDQ + h * HD + c8 * 8];
    *(u16x4*)&t[row][c8 * 8]     = u.q[0];
    *(u16x4*)&t[row][c8 * 8 + 4] = u.q[1];
  }
  __syncthreads();
  const int nq = tid & 15, dh = tid >> 4;
#pragma unroll
  for (int i = 0; i < 4; i++) {
    int d = i * 16 + dh;
    u16x4 pk; float s = 0.f;
#pragma unroll
    for (int j = 0; j < 4; j++) { u16 v = t[nq * 4 + j][d]; pk[j] = v; s += bf2f(v); }
    *(u16x4*)&vT[((long)bh * HD + d) * SEQ + n0 + nq * 4] = pk;
    s += __shfl_xor(s, 1); s += __shfl_xor(s, 2);
    s += __shfl_xor(s, 4); s += __shfl_xor(s, 8);
    if (nq == 0) atomicAdd(&vsum[bh * HD + d], s);
  }
}

// ---------------------------------------------------------------------------
// Fused key features + context partials, BARRIER-FREE. (CLOSED at 74 us.)
// kb is the k slice of qkv (row stride LDQ).
// ---------------------------------------------------------------------------
__global__ __launch_bounds__(256, 2) void k_fk_ctx(const u16* __restrict__ kb, const u16* __restrict__ vT,
                                                   const u16* __restrict__ projb, u16* __restrict__ part,
                                                   float* __restrict__ su, u32* __restrict__ stabEnc) {
  __shared__ __align__(16) u16 sU[4][64 * 64];   // per-wave 8KB regions
  const int ck = blockIdx.x, bh = blockIdx.y, b = bh >> 4, h = bh & 15;
  const int tid = threadIdx.x, w = tid >> 6, l = tid & 63;
  const int c = l & 15, g = l >> 4;
  u16* sUw = &sU[w][0];
  const int sw = c & 7;

  // proj B-fragments in registers: features w*64+nt*16+c, k = k0*32+g*8+j
  bf16x8 pf[4][2];
#pragma unroll
  for (int nt = 0; nt < 4; nt++)
#pragma unroll
    for (int k0 = 0; k0 < 2; k0++)
      pf[nt][k0] = *(const bf16x8*)&projb[(w * 64 + nt * 16 + c) * 64 + k0 * 32 + g * 8];

  f32x4 acc2[4][4]; ZERO_ACC(acc2);   // ctx: rows=features(wave-local), cols=d
  float suv[4] = {0.f, 0.f, 0.f, 0.f};
  float amax = -1e30f;                // max raw acc; stab = c1*amax (monotone)
  const long tok0 = (long)b * SEQ + ck * 256;

  for (int s = 0; s < 4; s++) {
    const long t0 = tok0 + s * 64;
    // A-fragments direct from global: token = mt*16+c, k(d) = k0*32+g*8+j
    bf16x8 af[4][2];
#pragma unroll
    for (int mt = 0; mt < 4; mt++)
#pragma unroll
      for (int k0 = 0; k0 < 2; k0++)
        af[mt][k0] = *(const bf16x8*)&kb[(t0 + mt * 16 + c) * LDQ + h * HD + k0 * 32 + g * 8];
    // hoist vT B-frags for the ctx GEMM: HBM/L3 latency hides under the
    // feature GEMM + epilogue below.
    bf16x8 vf[2][4];
#pragma unroll
    for (int k0 = 0; k0 < 2; k0++)
#pragma unroll
      for (int nt = 0; nt < 4; nt++)
        vf[k0][nt] = *(const bf16x8*)&vT[((long)bh * HD + nt * 16 + c) * SEQ +
                                         ck * 256 + s * 64 + k0 * 32 + g * 8];

    // per-token-granule mt: diag + one 16-row strip of the feature GEMM +
    // epilogue, with accR recycled (peak acc pressure 64+16 not 64+64).
#pragma unroll
    for (int mt = 0; mt < 4; mt++) {
      float ss = 0.f;
#pragma unroll
      for (int k0 = 0; k0 < 2; k0++)
#pragma unroll
        for (int j = 0; j < 8; j++) {
          float v = bf2f((u16)af[mt][k0][j]);
          ss += v * v;
        }
      ss += __shfl_xor(ss, 16);
      ss += __shfl_xor(ss, 32);
      const float dgrow = ss * 0.0625f;   // diag of token mt*16+c
      f32x4 accR[4];
#pragma unroll
      for (int nt = 0; nt < 4; nt++) accR[nt] = (f32x4)0.0f;
#pragma unroll
      for (int k0 = 0; k0 < 2; k0++)
#pragma unroll
        for (int nt = 0; nt < 4; nt++)
          accR[nt] = __builtin_amdgcn_mfma_f32_16x16x32_bf16(af[mt][k0], pf[nt][k0], accR[nt], 0, 0, 0);
      // epilogue: U = exp(c1*acc - diag) -> per-wave sU (swizzled), su, stab
      float dg[4];
#pragma unroll
      for (int r = 0; r < 4; r++) dg[r] = __shfl(dgrow, g * 4 + r);
#pragma unroll
      for (int nt = 0; nt < 4; nt++) {
        u16x4 pk;
#pragma unroll
        for (int r = 0; r < 4; r++) {
          float a = accR[nt][r];
          amax = fmaxf(amax, a);
          float U = __expf(fmaf(a, c1f(), -dg[r]));
          pk[r] = f2bf(U);
          suv[nt] += U;
        }
        // write tokens granule G=mt*4+g (pair P=mt*2+(g>>1), b=g&1), row nt*16+c
        *(u16x4*)&sUw[(nt * 16 + c) * 64 + (((mt * 2 + (g >> 1)) ^ sw) * 2 + (g & 1)) * 4] = pk;
      }
    }
    // ctx GEMM: acc2[m][d] += sum_n U^T[m][n] * vT[d][n]  (intra-wave sU reads)
#pragma unroll
    for (int k0 = 0; k0 < 2; k0++) {
      bf16x8 uf[4];
#pragma unroll
      for (int mt = 0; mt < 4; mt++)
        uf[mt] = *(const bf16x8*)&sUw[(mt * 16 + c) * 64 + ((k0 * 4 + g) ^ sw) * 8];
#pragma unroll
      for (int mt = 0; mt < 4; mt++)
#pragma unroll
        for (int nt = 0; nt < 4; nt++)
          acc2[mt][nt] = __builtin_amdgcn_mfma_f32_16x16x32_bf16(uf[mt], vf[k0][nt], acc2[mt][nt], 0, 0, 0);
    }
  }
  // store ctx partials bf16: part[z][m][d]
  const long zp = (long)(bh * 16 + ck);
#pragma unroll
  for (int mt = 0; mt < 4; mt++)
#pragma unroll
    for (int nt = 0; nt < 4; nt++)
#pragma unroll
      for (int r = 0; r < 4; r++) {
        int m = w * 64 + mt * 16 + g * 4 + r;
        int d = nt * 16 + c;
        part[(zp * NF + m) * HD + d] = f2bf(acc2[mt][nt][r]);
      }
  // su atomic (reduce over lane groups sharing c)
#pragma unroll
  for (int nt = 0; nt < 4; nt++) {
    float v = suv[nt];
    v += __shfl_xor(v, 16);
    v += __shfl_xor(v, 32);
    if (l < 16) atomicAdd(&su[bh * NF + w * 64 + nt * 16 + l], v);
  }
  for (int o = 32; o; o >>= 1) amax = fmaxf(amax, __shfl_xor(amax, o));
  if (l == 0) atomicMax(stabEnc, encf(c1f() * amax));
}

// ---------------------------------------------------------------------------
// Fused query features + attention. One block per (64-token tile, bh).
// qb is the q slice of qkv (row stride LDQ); attn_bf separate (stride EMB).
// ---------------------------------------------------------------------------
__global__ __launch_bounds__(256, 4) void k_fq_attn(const u16* __restrict__ qb, const u16* __restrict__ projb,
                                                    const float* __restrict__ k_sum, const float* __restrict__ ksum_tot,
                                                    const u16* __restrict__ ct_bf, const float* __restrict__ ctsum,
                                                    u16* __restrict__ attn_bf) {
  __shared__ __align__(16) u16 sUq[64 * 256];    // Uq [token][m], 16B-granule swizzled
  __shared__ float redmax[4][64];
  __shared__ float redsum[4][64];
  const int bh = blockIdx.y, b = bh >> 4, h = bh & 15;
  const long t0 = (long)b * SEQ + blockIdx.x * 64;
  const int tid = threadIdx.x, w = tid >> 6, l = tid & 63;
  const int lrow = l & 15, lk = (l >> 4) * 8, lr4 = (l >> 4) * 4, lc = l & 15;

  // A-frags: proj rows = features w*64+mt*16+lrow, k = k0*32+lk+j
  bf16x8 pf[4][2];
#pragma unroll
  for (int mt = 0; mt < 4; mt++)
#pragma unroll
    for (int k0 = 0; k0 < 2; k0++)
      pf[mt][k0] = *(const bf16x8*)&projb[(w * 64 + mt * 16 + lrow) * 64 + k0 * 32 + lk];
  // B-frags: q rows = tokens nt*16+lrow (direct from global, fk_ctx pattern).
  bf16x8 af[4][2];
#pragma unroll
  for (int nt = 0; nt < 4; nt++)
#pragma unroll
    for (int k0 = 0; k0 < 2; k0++)
      af[nt][k0] = *(const bf16x8*)&qb[(t0 + nt * 16 + lrow) * LDQ + h * HD + k0 * 32 + lk];

  // inline diag per token: each lane ends with diag of its OWN token nt*16+lc
  float dgq[4];
#pragma unroll
  for (int nt = 0; nt < 4; nt++) {
    float ss = 0.f;
#pragma unroll
    for (int k0 = 0; k0 < 2; k0++)
#pragma unroll
      for (int j = 0; j < 8; j++) {
        float v = bf2f((u16)af[nt][k0][j]);
        ss += v * v;
      }
    ss += __shfl_xor(ss, 16);
    ss += __shfl_xor(ss, 32);
    dgq[nt] = ss * 0.0625f;
  }

  // k_sum for this lane's 16 features (mt, lr4+r)
  f32x4 ksr[4];
#pragma unroll
  for (int mt = 0; mt < 4; mt++)
    ksr[mt] = *(const f32x4*)&k_sum[(long)bh * NF + w * 64 + mt * 16 + lr4];

  // per-token-granule nt: 16-col strip of the feature GEMM (accC recycled)
  // + epilogue: U -> sUq (u16x4 along features, swizzled), per-token max,
  // sum(U*ksum) partials.
#pragma unroll
  for (int nt = 0; nt < 4; nt++) {
    f32x4 accC[4];
#pragma unroll
    for (int mt = 0; mt < 4; mt++) accC[mt] = (f32x4)0.0f;
#pragma unroll
    for (int k0 = 0; k0 < 2; k0++)
#pragma unroll
      for (int mt = 0; mt < 4; mt++)
        accC[mt] = __builtin_amdgcn_mfma_f32_16x16x32_bf16(pf[mt][k0], af[nt][k0], accC[mt], 0, 0, 0);

    const int tok = nt * 16 + lc;
    const int trow = tok * NF, tsw = tok & 7;
    float vmax = -1e30f, s = 0.f;
#pragma unroll
    for (int mt = 0; mt < 4; mt++) {
      const int fb = w * 64 + mt * 16 + lr4;   // multiple of 4
      u16x4 pk;
#pragma unroll
      for (int r = 0; r < 4; r++) {
        float dd = c1f() * accC[mt][r];
        vmax = fmaxf(vmax, dd);
        float U = __expf(dd - dgq[nt]);
        pk[r] = f2bf(U);
        s += U * ksr[mt][r];
      }
      *(u16x4*)&sUq[trow + (((fb >> 3) ^ tsw) << 3) + (fb & 7)] = pk;
    }
    vmax = fmaxf(vmax, __shfl_xor(vmax, 16));
    vmax = fmaxf(vmax, __shfl_xor(vmax, 32));
    s += __shfl_xor(s, 16);
    s += __shfl_xor(s, 32);
    if (l < 16) { redmax[w][nt * 16 + l] = vmax; redsum[w][nt * 16 + l] = s; }
  }
  __syncthreads();
  // attention GEMM: wave w owns d in [w*16, w*16+16); K = 256 features
  f32x4 acc2[4];
#pragma unroll
  for (int mt = 0; mt < 4; mt++) acc2[mt] = (f32x4)0.0f;
#pragma unroll
  for (int kk = 0; kk < 8; kk++) {
    bf16x8 bfr = *(const bf16x8*)&ct_bf[((long)bh * HD + w * 16 + lrow) * NF + kk * 32 + lk];
#pragma unroll
    for (int mt = 0; mt < 4; mt++) {
      int row = mt * 16 + lrow;
      bf16x8 a2 = *(const bf16x8*)&sUq[row * NF + (((kk * 4 + (l >> 4)) ^ (row & 7)) * 8)];
      acc2[mt] = __builtin_amdgcn_mfma_f32_16x16x32_bf16(a2, bfr, acc2[mt], 0, 0, 0);
    }
  }
  // epilogue: alpha/beta per row, write bf16 attn in [B,N,E]
  const float kst = ksum_tot[bh];
  const float cts = ctsum[(long)bh * HD + w * 16 + lc];
#pragma unroll
  for (int mt = 0; mt < 4; mt++)
#pragma unroll
    for (int r = 0; r < 4; r++) {
      int row = mt * 16 + lr4 + r;
      float rs = fmaxf(fmaxf(redmax[0][row], redmax[1][row]),
                       fmaxf(redmax[2][row], redmax[3][row]));
      float S1 = redsum[0][row] + redsum[1][row] + redsum[2][row] + redsum[3][row];
      float ers = __expf(-rs);
      float di = 1.0f / (ratf() * (ers * S1 + kepsf() * kst));
      float a_ = di * ratf() * ers;
      float b_ = di * ratf() * kepsf();
      float ov = a_ * acc2[mt][r] + b_ * cts;
      attn_bf[(t0 + row) * EMB + h * HD + w * 16 + lc] = f2bf(ov);
    }
}

// --------------------------- glue kernels ----------------------------------
__global__ void k_cvt(const float* __restrict__ s, u16* __restrict__ d, long n4) {
  long i = (long)blockIdx.x * blockDim.x + threadIdx.x;
  if (i >= n4) return;
  float4 v = ((const float4*)s)[i];
  u16x4 o = { f2bf(v.x), f2bf(v.y), f2bf(v.z), f2bf(v.w) };
  ((u16x4*)d)[i] = o;
}

__global__ void k_init(float* su, float* vsum, u32* stabEnc) {
  int i = blockIdx.x * 256 + threadIdx.x;
  if (i < BHN * NF) su[i] = 0.f;
  if (i < BHN * HD) vsum[i] = 0.f;
  if (i == 0) *stabEnc = 0u;
}

// k_sum[m] = ratio*(e^-stab*su[m] + eps*SEQ); ksum_tot = sum_m k_sum
__global__ __launch_bounds__(256) void k_asm_ksum(const float* __restrict__ su, const u32* __restrict__ stabEnc,
                                                  float* __restrict__ k_sum, float* __restrict__ ksum_tot) {
  __shared__ float red[256];
  int z = blockIdx.x, m = threadIdx.x;
  float es = __expf(-decf(*stabEnc));
  float v = ratf() * (es * su[(long)z * NF + m] + kepsf() * (float)SEQ);
  k_sum[(long)z * NF + m] = v;
  red[m] = v;
  __syncthreads();
  for (int s = 128; s > 0; s >>= 1) {
    if (m < s) red[m] += red[m + s];
    __syncthreads();
  }
  if (m == 0) ksum_tot[z] = red[0];
}

// ct[d][m] = ratio*(e^-stab*sum_ck part[m][d] + eps*vsum[d]) -> bf16; ctsum[d]
__global__ __launch_bounds__(256) void k_asm_ct(const u16* __restrict__ part, const float* __restrict__ vsum,
                                                const u32* __restrict__ stabEnc, u16* __restrict__ ct_bf,
                                                float* __restrict__ ctsum) {
  __shared__ float red[4][64];
  const int z = blockIdx.x, tid = threadIdx.x;
  const int w = tid >> 6, l = tid & 63;
  float es = __expf(-decf(*stabEnc));
  float vs = vsum[(long)z * HD + l];
  float csum = 0.f;
  for (int m = w; m < NF; m += 4) {
    float a = 0.f;
#pragma unroll
    for (int ck = 0; ck < 16; ck++)
      a += bf2f(part[((long)(z * 16 + ck) * NF + m) * HD + l]);
    float cv = ratf() * (es * a + kepsf() * vs);
    ct_bf[((long)z * HD + l) * NF + m] = f2bf(cv);
    csum += cv;
  }
  red[w][l] = csum;
  __syncthreads();
  if (tid < 64)
    ctsum[(long)z * HD + tid] = red[0][tid] + red[1][tid] + red[2][tid] + red[3][tid];
}

// ---------------------------------------------------------------------------
extern "C" void kernel_launch(void* const* d_in, const int* in_sizes, int n_in,
                              void* d_out, int out_size, void* d_ws, size_t ws_size,
                              hipStream_t stream) {
  const float* x    = (const float*)d_in[0];
  const float* Wq   = (const float*)d_in[1];
  const float* bq   = (const float*)d_in[2];
  const float* Wk   = (const float*)d_in[3];
  const float* bk   = (const float*)d_in[4];
  const float* Wv   = (const float*)d_in[5];
  const float* bv   = (const float*)d_in[6];
  const float* Wo   = (const float*)d_in[7];
  const float* bo   = (const float*)d_in[8];
  const float* proj = (const float*)d_in[9];

  char* base = (char*)d_ws;
  size_t off = 0;
  auto alloc = [&](size_t bytes) {
    off = (off + 255) & ~(size_t)255;
    char* r = base + off;
    off += bytes;
    return r;
  };
  // ~145 MB total: qkv fused, attn_bf aliased to xb.
  u16*  xb     = (u16*)alloc((size_t)TOKN * EMB * 2);   // 33.5 MB; -> part -> attn_bf
  u16*  wqkv   = (u16*)alloc((size_t)3 * EMB * EMB * 2);// 6 MB [Wq;Wk;Wv]
  u16*  wob    = (u16*)alloc((size_t)EMB * EMB * 2);
  u16*  projb  = (u16*)alloc((size_t)NF * HD * 2);
  u16*  qkv    = (u16*)alloc((size_t)TOKN * LDQ * 2);   // 100.7 MB fused output
  float* su    = (float*)alloc((size_t)BHN * NF * 4);
  float* k_sum = (float*)alloc((size_t)BHN * NF * 4);
  float* ksum_t= (float*)alloc((size_t)BHN * 4);
  float* vsum  = (float*)alloc((size_t)BHN * HD * 4);
  float* ctsum = (float*)alloc((size_t)BHN * HD * 4);
  u32*  stabE  = (u32*)alloc(256);
  u16*  ct_bf  = (u16*)alloc((size_t)BHN * HD * NF * 2); // 2 MB
  u16*  qb     = qkv;              // column slices, row stride LDQ
  u16*  kb     = qkv + EMB;
  u16*  vb     = qkv + 2 * EMB;
  u16*  part   = xb;               // xb dead after QKV GEMM
  u16*  attn_bf= xb;               // part dead after k_asm_ct (step 6)
  u16*  vT     = (u16*)d_out;      // d_out scratch until final GEMM

  // 0. init atomic accumulators
  k_init<<<64, 256, 0, stream>>>(su, vsum, stabE);
  // 1. fp32 -> bf16
  k_cvt<<<(TOKN * EMB / 4 + 255) / 256, 256, 0, stream>>>(x, xb, (long)TOKN * EMB / 4);
  k_cvt<<<(EMB * EMB / 4 + 255) / 256, 256, 0, stream>>>(Wq, wqkv, (long)EMB * EMB / 4);
  k_cvt<<<(EMB * EMB / 4 + 255) / 256, 256, 0, stream>>>(Wk, wqkv + (size_t)EMB * EMB, (long)EMB * EMB / 4);
  k_cvt<<<(EMB * EMB / 4 + 255) / 256, 256, 0, stream>>>(Wv, wqkv + (size_t)2 * EMB * EMB, (long)EMB * EMB / 4);
  k_cvt<<<(EMB * EMB / 4 + 255) / 256, 256, 0, stream>>>(Wo, wob, (long)EMB * EMB / 4);
  k_cvt<<<(NF * HD / 4 + 255) / 256, 256, 0, stream>>>(proj, projb, (long)NF * HD / 4);
  // 2. fused QKV projection: [16384][3072] = xb * [Wq;Wk;Wv]^T + bias
  k_gemm3<<<dim3(LDQ / 128, TOKN / 128), 256, 0, stream>>>(xb, wqkv, qkv, bq, bk, bv,
                                                           EMB, EMB, EMB, LDQ);
  // 3. v transpose into d_out scratch + vsum
  k_vT<<<dim3(SEQ / 64, BHN), 256, 0, stream>>>(vb, vT, vsum);
  // 4. fused key features + context partials (writes part=xb after xb dead)
  k_fk_ctx<<<dim3(16, BHN), 256, 0, stream>>>(kb, vT, projb, part, su, stabE);
  // 5. assemble k_sum / ksum_tot
  k_asm_ksum<<<BHN, 256, 0, stream>>>(su, stabE, k_sum, ksum_t);
  // 6. assemble context (bf16) + ctsum
  k_asm_ct<<<BHN, 256, 0, stream>>>(part, vsum, stabE, ct_bf, ctsum);
  // 7. fused query features + attention (writes attn_bf=xb after part dead)
  k_fq_attn<<<dim3(SEQ / 64, BHN), 256, 0, stream>>>(qb, projb, k_sum, ksum_t, ct_bf, ctsum, attn_bf);
  // 8. output projection (fp32 out, overwrites vT scratch region)
  k_gemm<false><<<dim3(EMB / 128, TOKN / 128), 256, 0, stream>>>(attn_bf, wob, d_out, bo, EMB, EMB, EMB, EMB);
}

// Round 13
// 501.900 us; speedup vs baseline: 1.6006x; 1.0221x over previous
//
#include <hip/hip_runtime.h>
#include <hip/hip_bf16.h>
#include <stdint.h>

// Performer (FAVOR+) forward, MI355X/gfx950.
// B=4, N=4096, E=1024, H=16, D=64, M(features)=256.
// bf16 MFMA (16x16x32) everywhere matmul-shaped, fp32 accumulate/epilogues.
// kf never materialized: kf = ratio*(e^-stab * U + eps), U = exp(dd-diag) is
// stab-free; context/k_sum assembled linearly from fused U^T·v and U^T·1.
// R3: fk_ctx barrier-free. R4: fq_attn operand-swap; XCD swizzle.
// R5: fk_ctx accR strip (85.5->74us). R6: fq_attn spill fix (578->563us).
// R7/R8/R9 FAILED (spill). R10 revert = 560.7us; fk_ctx CLOSED.
// R11: QKV fused into k_gemm3. MEASURED 554.2us (k_gemm3 155us exposed).
// R12: BK=64 + both-sides granule-XOR swizzle. MEASURED 513.0us; k_gemm3
// 142.7us/720TF, bank-conflict 12.6M -> 0, no spill. Still latency-bound
// (Mfma 31%, VALU 44%, HBM 24%): 16 per-K-step vmcnt(0)+barrier drains.
// R13: counted-vmcnt double-buffer pipeline (T3/T4 idiom, m201/m218):
// LDS 2x(sA+sB)=64KB; per K-step issue tile t+1's 8 loads/thread, then
// raw `s_waitcnt vmcnt(8)` (waits ONLY tile t) + raw s_barrier -> prefetch
// stays in flight across the barrier (never drain to 0 mid-loop).
// sched_barrier(0) fence per rule #18. Zero extra registers. Both k_gemm3
// and k_gemm inherit. Pre-commit (rule #23): positive->confirmed; null->
// inconclusive (m139 was null in a different occupancy/K regime).

#define TOKN  16384
#define SEQ   4096
#define EMB   1024
#define LDQ   3072   // fused qkv row stride
#define NHEAD 16
#define HD    64
#define NF    256
#define BHN   64   // batch*heads

static __device__ __forceinline__ constexpr float c1f()  { return 0.35355339059327379f; } // 64^-0.25
static __device__ __forceinline__ constexpr float ratf() { return 0.0625f; }              // 256^-0.5
static __device__ __forceinline__ constexpr float kepsf(){ return 1e-4f; }

typedef unsigned short u16;
typedef unsigned int   u32;
typedef __attribute__((ext_vector_type(8))) short bf16x8;
typedef __attribute__((ext_vector_type(4))) float f32x4;
typedef __attribute__((ext_vector_type(4))) u16   u16x4;

union U8 { bf16x8 v8; u16x4 q[2]; };

__device__ __forceinline__ float bf2f(u16 u) { return __uint_as_float(((u32)u) << 16); }
__device__ __forceinline__ u16 f2bf(float f) {
  u32 u = __float_as_uint(f);
  u += 0x7fffu + ((u >> 16) & 1u);   // RNE
  return (u16)(u >> 16);
}
// order-preserving float<->uint encoding for atomicMax on a float
__device__ __forceinline__ u32 encf(float f) {
  u32 u = __float_as_uint(f);
  return (u & 0x80000000u) ? ~u : (u | 0x80000000u);
}
__device__ __forceinline__ float decf(u32 e) {
  u32 u = (e & 0x80000000u) ? (e & 0x7fffffffu) : ~e;
  return __uint_as_float(u);
}

__device__ __forceinline__ void gl2lds16(const u16* g, void* l) {
  __builtin_amdgcn_global_load_lds(
      (const __attribute__((address_space(1))) u32*)g,
      (__attribute__((address_space(3))) u32*)l, 16, 0, 0);
}

#define ZERO_ACC(acc)                         \
  _Pragma("unroll") for (int _i = 0; _i < 4; _i++) \
  _Pragma("unroll") for (int _j = 0; _j < 4; _j++) acc[_i][_j] = (f32x4)0.0f;

// ---------------------------------------------------------------------------
// MFMA GEMM core, R13: BK=64, double-buffered LDS, counted-vmcnt pipeline.
// C[m][n] += sum_k A[m][k]*B[n][k] (both row-major, K contiguous).
// 256 thr = 4 waves; wave tile 64x64 (4x4 of 16x16x32).
// Staging pre-permutes the global source granule (part ^ (row&7)) so the
// linear global_load_lds dest equals the swizzled layout; ds_read XORs the
// same involution -> conflict-free b128 reads (verified: conflicts 0, R12).
// Pipeline: stage(t+1) -> vmcnt(8) [tile t landed, t+1 in flight] ->
// s_barrier -> compute(buf t) -> s_barrier [readers done before t+2 writes].
// sA/sB must be sized 2*BM*64 / 2*BN*64 (two buffers).
// ---------------------------------------------------------------------------
template <int BM, int BN>
__device__ __forceinline__ void gemm_core(const u16* __restrict__ Ag, long lda,
                                          const u16* __restrict__ Bg, long ldb,
                                          int K, u16* sA, u16* sB,
                                          f32x4 (&acc)[4][4]) {
  const int tid = threadIdx.x;
  const int w = tid >> 6, l = tid & 63;
  constexpr int WM = BM / 64;
  const int wm = w % WM, wn = w / WM;
  const int lrow = l & 15, g4 = l >> 4;    // g4 = 16B-granule index in K-half
  constexpr int AI = (BM * 8) / 256;       // 16B chunks per tile / 256 thr
  constexpr int BI = (BN * 8) / 256;
  static_assert(AI + BI == 8, "vmcnt(8) literal assumes 8 loads/thread/tile");
  constexpr int ABUF = BM * 64;            // u16 elems per buffer
  constexpr int BBUF = BN * 64;

  auto stage = [&](int k0, int sel) {
#pragma unroll
    for (int i = 0; i < AI; i++) {
      int q = i * 256 + tid;
      int row = q >> 3, part = (q & 7) ^ (row & 7);   // inverse-swz source
      gl2lds16(Ag + (long)row * lda + k0 + part * 8,
               (char*)(sA + sel * ABUF) + i * 4096 + w * 1024);
    }
#pragma unroll
    for (int i = 0; i < BI; i++) {
      int q = i * 256 + tid;
      int row = q >> 3, part = (q & 7) ^ (row & 7);
      gl2lds16(Bg + (long)row * ldb + k0 + part * 8,
               (char*)(sB + sel * BBUF) + i * 4096 + w * 1024);
    }
  };

  stage(0, 0);
  const int NT = K >> 6;
  for (int t = 0; t < NT; ++t) {
    const int sel = t & 1;
    if (t + 1 < NT) {
      stage((t + 1) * 64, sel ^ 1);
      asm volatile("s_waitcnt vmcnt(8)" ::: "memory");   // tile t landed; t+1 in flight
    } else {
      asm volatile("s_waitcnt vmcnt(0)" ::: "memory");   // epilogue drain
    }
    __builtin_amdgcn_s_barrier();
    __builtin_amdgcn_sched_barrier(0);
    const u16* pA = sA + sel * ABUF;
    const u16* pB = sB + sel * BBUF;
#pragma unroll
    for (int kk = 0; kk < 2; kk++) {
      bf16x8 af[4], bfr[4];
#pragma unroll
      for (int mt = 0; mt < 4; mt++) {
        int row = wm * 64 + mt * 16 + lrow;
        af[mt] = *(const bf16x8*)(pA + row * 64 + (((kk * 4 + g4) ^ (row & 7)) * 8));
      }
#pragma unroll
      for (int nt = 0; nt < 4; nt++) {
        int row = wn * 64 + nt * 16 + lrow;
        bfr[nt] = *(const bf16x8*)(pB + row * 64 + (((kk * 4 + g4) ^ (row & 7)) * 8));
      }
#pragma unroll
      for (int mt = 0; mt < 4; mt++)
#pragma unroll
        for (int nt = 0; nt < 4; nt++)
          acc[mt][nt] = __builtin_amdgcn_mfma_f32_16x16x32_bf16(af[mt], bfr[nt], acc[mt][nt], 0, 0, 0);
    }
    __builtin_amdgcn_s_barrier();   // readers done before tile t+2 overwrites this buffer
  }
}

// ---------------------------------------------------------------------------
// Big 128x128 GEMM: C = A*B^T + bias. XCD-aware block swizzle.
// ---------------------------------------------------------------------------
template <bool BF16OUT>
__global__ __launch_bounds__(256) void k_gemm(const u16* __restrict__ A, const u16* __restrict__ Bw,
                                              void* __restrict__ Cout, const float* __restrict__ bias,
                                              int K, int lda, int ldb, int ldc) {
  __shared__ __align__(16) u16 sA[2 * 128 * 64];
  __shared__ __align__(16) u16 sB[2 * 128 * 64];
  const int nbx = gridDim.x;
  const int nwg = nbx * gridDim.y;
  int lin = blockIdx.y * nbx + blockIdx.x;
  if ((nwg & 7) == 0) {                    // bijective XCD swizzle (nwg%8==0)
    int per = nwg >> 3;
    lin = (lin & 7) * per + (lin >> 3);
  }
  const int m0 = (lin / nbx) * 128, n0 = (lin % nbx) * 128;
  f32x4 acc[4][4]; ZERO_ACC(acc);
  gemm_core<128, 128>(A + (long)m0 * lda, lda, Bw + (long)n0 * ldb, ldb, K, sA, sB, acc);
  const int l = threadIdx.x & 63, w = threadIdx.x >> 6;
  const int wm = w & 1, wn = w >> 1, lr4 = (l >> 4) * 4, lc = l & 15;
#pragma unroll
  for (int nt = 0; nt < 4; nt++) {
    int gcol = n0 + wn * 64 + nt * 16 + lc;
    float bia = bias[gcol];
#pragma unroll
    for (int mt = 0; mt < 4; mt++)
#pragma unroll
      for (int r = 0; r < 4; r++) {
        int grow = m0 + wm * 64 + mt * 16 + lr4 + r;
        float v = acc[mt][nt][r] + bia;
        if (BF16OUT) ((u16*)Cout)[(long)grow * ldc + gcol] = f2bf(v);
        else         ((float*)Cout)[(long)grow * ldc + gcol] = v;
      }
  }
}

// ---------------------------------------------------------------------------
// R11: fused QKV GEMM. C[16384][3072] = xb * [Wq;Wk;Wv]^T + [bq|bk|bv].
// Weight rows 0..1023 = Wq, 1024..2047 = Wk, 2048..3071 = Wv. Blocks never
// straddle a 1024-col boundary (1024 % 128 == 0) -> bias segment per block.
// ---------------------------------------------------------------------------
__global__ __launch_bounds__(256) void k_gemm3(const u16* __restrict__ A, const u16* __restrict__ Bw,
                                               u16* __restrict__ Cout,
                                               const float* __restrict__ b0, const float* __restrict__ b1,
                                               const float* __restrict__ b2,
                                               int K, int lda, int ldb, int ldc) {
  __shared__ __align__(16) u16 sA[2 * 128 * 64];
  __shared__ __align__(16) u16 sB[2 * 128 * 64];
  const int nbx = gridDim.x;
  const int nwg = nbx * gridDim.y;
  int lin = blockIdx.y * nbx + blockIdx.x;
  if ((nwg & 7) == 0) {                    // bijective XCD swizzle (nwg%8==0)
    int per = nwg >> 3;
    lin = (lin & 7) * per + (lin >> 3);
  }
  const int m0 = (lin / nbx) * 128, n0 = (lin % nbx) * 128;
  f32x4 acc[4][4]; ZERO_ACC(acc);
  gemm_core<128, 128>(A + (long)m0 * lda, lda, Bw + (long)n0 * ldb, ldb, K, sA, sB, acc);
  const int l = threadIdx.x & 63, w = threadIdx.x >> 6;
  const int wm = w & 1, wn = w >> 1, lr4 = (l >> 4) * 4, lc = l & 15;
  const int seg = n0 >> 10;
  const float* bias = seg == 0 ? b0 : (seg == 1 ? b1 : b2);
#pragma unroll
  for (int nt = 0; nt < 4; nt++) {
    int gcol = n0 + wn * 64 + nt * 16 + lc;
    float bia = bias[gcol & 1023];
#pragma unroll
    for (int mt = 0; mt < 4; mt++)
#pragma unroll
      for (int r = 0; r < 4; r++) {
        int grow = m0 + wm * 64 + mt * 16 + lr4 + r;
        Cout[(long)grow * ldc + gcol] = f2bf(acc[mt][nt][r] + bia);
      }
  }
}

// ---------------------------------------------------------------------------
// v transpose: v slice of qkv [tok][LDQ] -> vT[bh][d][n] (bf16), plus vsum.
// ---------------------------------------------------------------------------
__global__ __launch_bounds__(256) void k_vT(const u16* __restrict__ vb, u16* __restrict__ vT,
                                            float* __restrict__ vsum) {
  __shared__ u16 t[64][72];   // 72 stride: 8B-aligned rows, conflict-benign
  const int bh = blockIdx.y, n0 = blockIdx.x * 64, b = bh >> 4, h = bh & 15;
  const int tid = threadIdx.x;
#pragma unroll
  for (int i = 0; i < 2; i++) {
    int idx = i * 256 + tid, row = idx >> 3, c8 = idx & 7;
    U8 u;
    u.v8 = *(const bf16x8*)&vb[((long)(b * SEQ) + n0 + row) * LDQ + h * HD + c8 * 8];
    *(u16x4*)&t[row][c8 * 8]     = u.q[0];
    *(u16x4*)&t[row][c8 * 8 + 4] = u.q[1];
  }
  __syncthreads();
  const int nq = tid & 15, dh = tid >> 4;
#pragma unroll
  for (int i = 0; i < 4; i++) {
    int d = i * 16 + dh;
    u16x4 pk; float s = 0.f;
#pragma unroll
    for (int j = 0; j < 4; j++) { u16 v = t[nq * 4 + j][d]; pk[j] = v; s += bf2f(v); }
    *(u16x4*)&vT[((long)bh * HD + d) * SEQ + n0 + nq * 4] = pk;
    s += __shfl_xor(s, 1); s += __shfl_xor(s, 2);
    s += __shfl_xor(s, 4); s += __shfl_xor(s, 8);
    if (nq == 0) atomicAdd(&vsum[bh * HD + d], s);
  }
}

// ---------------------------------------------------------------------------
// Fused key features + context partials, BARRIER-FREE. (CLOSED at 74 us.)
// kb is the k slice of qkv (row stride LDQ).
// ---------------------------------------------------------------------------
__global__ __launch_bounds__(256, 2) void k_fk_ctx(const u16* __restrict__ kb, const u16* __restrict__ vT,
                                                   const u16* __restrict__ projb, u16* __restrict__ part,
                                                   float* __restrict__ su, u32* __restrict__ stabEnc) {
  __shared__ __align__(16) u16 sU[4][64 * 64];   // per-wave 8KB regions
  const int ck = blockIdx.x, bh = blockIdx.y, b = bh >> 4, h = bh & 15;
  const int tid = threadIdx.x, w = tid >> 6, l = tid & 63;
  const int c = l & 15, g = l >> 4;
  u16* sUw = &sU[w][0];
  const int sw = c & 7;

  // proj B-fragments in registers: features w*64+nt*16+c, k = k0*32+g*8+j
  bf16x8 pf[4][2];
#pragma unroll
  for (int nt = 0; nt < 4; nt++)
#pragma unroll
    for (int k0 = 0; k0 < 2; k0++)
      pf[nt][k0] = *(const bf16x8*)&projb[(w * 64 + nt * 16 + c) * 64 + k0 * 32 + g * 8];

  f32x4 acc2[4][4]; ZERO_ACC(acc2);   // ctx: rows=features(wave-local), cols=d
  float suv[4] = {0.f, 0.f, 0.f, 0.f};
  float amax = -1e30f;                // max raw acc; stab = c1*amax (monotone)
  const long tok0 = (long)b * SEQ + ck * 256;

  for (int s = 0; s < 4; s++) {
    const long t0 = tok0 + s * 64;
    // A-fragments direct from global: token = mt*16+c, k(d) = k0*32+g*8+j
    bf16x8 af[4][2];
#pragma unroll
    for (int mt = 0; mt < 4; mt++)
#pragma unroll
      for (int k0 = 0; k0 < 2; k0++)
        af[mt][k0] = *(const bf16x8*)&kb[(t0 + mt * 16 + c) * LDQ + h * HD + k0 * 32 + g * 8];
    // hoist vT B-frags for the ctx GEMM: HBM/L3 latency hides under the
    // feature GEMM + epilogue below.
    bf16x8 vf[2][4];
#pragma unroll
    for (int k0 = 0; k0 < 2; k0++)
#pragma unroll
      for (int nt = 0; nt < 4; nt++)
        vf[k0][nt] = *(const bf16x8*)&vT[((long)bh * HD + nt * 16 + c) * SEQ +
                                         ck * 256 + s * 64 + k0 * 32 + g * 8];

    // per-token-granule mt: diag + one 16-row strip of the feature GEMM +
    // epilogue, with accR recycled (peak acc pressure 64+16 not 64+64).
#pragma unroll
    for (int mt = 0; mt < 4; mt++) {
      float ss = 0.f;
#pragma unroll
      for (int k0 = 0; k0 < 2; k0++)
#pragma unroll
        for (int j = 0; j < 8; j++) {
          float v = bf2f((u16)af[mt][k0][j]);
          ss += v * v;
        }
      ss += __shfl_xor(ss, 16);
      ss += __shfl_xor(ss, 32);
      const float dgrow = ss * 0.0625f;   // diag of token mt*16+c
      f32x4 accR[4];
#pragma unroll
      for (int nt = 0; nt < 4; nt++) accR[nt] = (f32x4)0.0f;
#pragma unroll
      for (int k0 = 0; k0 < 2; k0++)
#pragma unroll
        for (int nt = 0; nt < 4; nt++)
          accR[nt] = __builtin_amdgcn_mfma_f32_16x16x32_bf16(af[mt][k0], pf[nt][k0], accR[nt], 0, 0, 0);
      // epilogue: U = exp(c1*acc - diag) -> per-wave sU (swizzled), su, stab
      float dg[4];
#pragma unroll
      for (int r = 0; r < 4; r++) dg[r] = __shfl(dgrow, g * 4 + r);
#pragma unroll
      for (int nt = 0; nt < 4; nt++) {
        u16x4 pk;
#pragma unroll
        for (int r = 0; r < 4; r++) {
          float a = accR[nt][r];
          amax = fmaxf(amax, a);
          float U = __expf(fmaf(a, c1f(), -dg[r]));
          pk[r] = f2bf(U);
          suv[nt] += U;
        }
        // write tokens granule G=mt*4+g (pair P=mt*2+(g>>1), b=g&1), row nt*16+c
        *(u16x4*)&sUw[(nt * 16 + c) * 64 + (((mt * 2 + (g >> 1)) ^ sw) * 2 + (g & 1)) * 4] = pk;
      }
    }
    // ctx GEMM: acc2[m][d] += sum_n U^T[m][n] * vT[d][n]  (intra-wave sU reads)
#pragma unroll
    for (int k0 = 0; k0 < 2; k0++) {
      bf16x8 uf[4];
#pragma unroll
      for (int mt = 0; mt < 4; mt++)
        uf[mt] = *(const bf16x8*)&sUw[(mt * 16 + c) * 64 + ((k0 * 4 + g) ^ sw) * 8];
#pragma unroll
      for (int mt = 0; mt < 4; mt++)
#pragma unroll
        for (int nt = 0; nt < 4; nt++)
          acc2[mt][nt] = __builtin_amdgcn_mfma_f32_16x16x32_bf16(uf[mt], vf[k0][nt], acc2[mt][nt], 0, 0, 0);
    }
  }
  // store ctx partials bf16: part[z][m][d]
  const long zp = (long)(bh * 16 + ck);
#pragma unroll
  for (int mt = 0; mt < 4; mt++)
#pragma unroll
    for (int nt = 0; nt < 4; nt++)
#pragma unroll
      for (int r = 0; r < 4; r++) {
        int m = w * 64 + mt * 16 + g * 4 + r;
        int d = nt * 16 + c;
        part[(zp * NF + m) * HD + d] = f2bf(acc2[mt][nt][r]);
      }
  // su atomic (reduce over lane groups sharing c)
#pragma unroll
  for (int nt = 0; nt < 4; nt++) {
    float v = suv[nt];
    v += __shfl_xor(v, 16);
    v += __shfl_xor(v, 32);
    if (l < 16) atomicAdd(&su[bh * NF + w * 64 + nt * 16 + l], v);
  }
  for (int o = 32; o; o >>= 1) amax = fmaxf(amax, __shfl_xor(amax, o));
  if (l == 0) atomicMax(stabEnc, encf(c1f() * amax));
}

// ---------------------------------------------------------------------------
// Fused query features + attention. One block per (64-token tile, bh).
// qb is the q slice of qkv (row stride LDQ); attn_bf separate (stride EMB).
// ---------------------------------------------------------------------------
__global__ __launch_bounds__(256, 4) void k_fq_attn(const u16* __restrict__ qb, const u16* __restrict__ projb,
                                                    const float* __restrict__ k_sum, const float* __restrict__ ksum_tot,
                                                    const u16* __restrict__ ct_bf, const float* __restrict__ ctsum,
                                                    u16* __restrict__ attn_bf) {
  __shared__ __align__(16) u16 sUq[64 * 256];    // Uq [token][m], 16B-granule swizzled
  __shared__ float redmax[4][64];
  __shared__ float redsum[4][64];
  const int bh = blockIdx.y, b = bh >> 4, h = bh & 15;
  const long t0 = (long)b * SEQ + blockIdx.x * 64;
  const int tid = threadIdx.x, w = tid >> 6, l = tid & 63;
  const int lrow = l & 15, lk = (l >> 4) * 8, lr4 = (l >> 4) * 4, lc = l & 15;

  // A-frags: proj rows = features w*64+mt*16+lrow, k = k0*32+lk+j
  bf16x8 pf[4][2];
#pragma unroll
  for (int mt = 0; mt < 4; mt++)
#pragma unroll
    for (int k0 = 0; k0 < 2; k0++)
      pf[mt][k0] = *(const bf16x8*)&projb[(w * 64 + mt * 16 + lrow) * 64 + k0 * 32 + lk];
  // B-frags: q rows = tokens nt*16+lrow (direct from global, fk_ctx pattern).
  bf16x8 af[4][2];
#pragma unroll
  for (int nt = 0; nt < 4; nt++)
#pragma unroll
    for (int k0 = 0; k0 < 2; k0++)
      af[nt][k0] = *(const bf16x8*)&qb[(t0 + nt * 16 + lrow) * LDQ + h * HD + k0 * 32 + lk];

  // inline diag per token: each lane ends with diag of its OWN token nt*16+lc
  float dgq[4];
#pragma unroll
  for (int nt = 0; nt < 4; nt++) {
    float ss = 0.f;
#pragma unroll
    for (int k0 = 0; k0 < 2; k0++)
#pragma unroll
      for (int j = 0; j < 8; j++) {
        float v = bf2f((u16)af[nt][k0][j]);
        ss += v * v;
      }
    ss += __shfl_xor(ss, 16);
    ss += __shfl_xor(ss, 32);
    dgq[nt] = ss * 0.0625f;
  }

  // k_sum for this lane's 16 features (mt, lr4+r)
  f32x4 ksr[4];
#pragma unroll
  for (int mt = 0; mt < 4; mt++)
    ksr[mt] = *(const f32x4*)&k_sum[(long)bh * NF + w * 64 + mt * 16 + lr4];

  // per-token-granule nt: 16-col strip of the feature GEMM (accC recycled)
  // + epilogue: U -> sUq (u16x4 along features, swizzled), per-token max,
  // sum(U*ksum) partials.
#pragma unroll
  for (int nt = 0; nt < 4; nt++) {
    f32x4 accC[4];
#pragma unroll
    for (int mt = 0; mt < 4; mt++) accC[mt] = (f32x4)0.0f;
#pragma unroll
    for (int k0 = 0; k0 < 2; k0++)
#pragma unroll
      for (int mt = 0; mt < 4; mt++)
        accC[mt] = __builtin_amdgcn_mfma_f32_16x16x32_bf16(pf[mt][k0], af[nt][k0], accC[mt], 0, 0, 0);

    const int tok = nt * 16 + lc;
    const int trow = tok * NF, tsw = tok & 7;
    float vmax = -1e30f, s = 0.f;
#pragma unroll
    for (int mt = 0; mt < 4; mt++) {
      const int fb = w * 64 + mt * 16 + lr4;   // multiple of 4
      u16x4 pk;
#pragma unroll
      for (int r = 0; r < 4; r++) {
        float dd = c1f() * accC[mt][r];
        vmax = fmaxf(vmax, dd);
        float U = __expf(dd - dgq[nt]);
        pk[r] = f2bf(U);
        s += U * ksr[mt][r];
      }
      *(u16x4*)&sUq[trow + (((fb >> 3) ^ tsw) << 3) + (fb & 7)] = pk;
    }
    vmax = fmaxf(vmax, __shfl_xor(vmax, 16));
    vmax = fmaxf(vmax, __shfl_xor(vmax, 32));
    s += __shfl_xor(s, 16);
    s += __shfl_xor(s, 32);
    if (l < 16) { redmax[w][nt * 16 + l] = vmax; redsum[w][nt * 16 + l] = s; }
  }
  __syncthreads();
  // attention GEMM: wave w owns d in [w*16, w*16+16); K = 256 features
  f32x4 acc2[4];
#pragma unroll
  for (int mt = 0; mt < 4; mt++) acc2[mt] = (f32x4)0.0f;
#pragma unroll
  for (int kk = 0; kk < 8; kk++) {
    bf16x8 bfr = *(const bf16x8*)&ct_bf[((long)bh * HD + w * 16 + lrow) * NF + kk * 32 + lk];
#pragma unroll
    for (int mt = 0; mt < 4; mt++) {
      int row = mt * 16 + lrow;
      bf16x8 a2 = *(const bf16x8*)&sUq[row * NF + (((kk * 4 + (l >> 4)) ^ (row & 7)) * 8)];
      acc2[mt] = __builtin_amdgcn_mfma_f32_16x16x32_bf16(a2, bfr, acc2[mt], 0, 0, 0);
    }
  }
  // epilogue: alpha/beta per row, write bf16 attn in [B,N,E]
  const float kst = ksum_tot[bh];
  const float cts = ctsum[(long)bh * HD + w * 16 + lc];
#pragma unroll
  for (int mt = 0; mt < 4; mt++)
#pragma unroll
    for (int r = 0; r < 4; r++) {
      int row = mt * 16 + lr4 + r;
      float rs = fmaxf(fmaxf(redmax[0][row], redmax[1][row]),
                       fmaxf(redmax[2][row], redmax[3][row]));
      float S1 = redsum[0][row] + redsum[1][row] + redsum[2][row] + redsum[3][row];
      float ers = __expf(-rs);
      float di = 1.0f / (ratf() * (ers * S1 + kepsf() * kst));
      float a_ = di * ratf() * ers;
      float b_ = di * ratf() * kepsf();
      float ov = a_ * acc2[mt][r] + b_ * cts;
      attn_bf[(t0 + row) * EMB + h * HD + w * 16 + lc] = f2bf(ov);
    }
}

// --------------------------- glue kernels ----------------------------------
__global__ void k_cvt(const float* __restrict__ s, u16* __restrict__ d, long n4) {
  long i = (long)blockIdx.x * blockDim.x + threadIdx.x;
  if (i >= n4) return;
  float4 v = ((const float4*)s)[i];
  u16x4 o = { f2bf(v.x), f2bf(v.y), f2bf(v.z), f2bf(v.w) };
  ((u16x4*)d)[i] = o;
}

__global__ void k_init(float* su, float* vsum, u32* stabEnc) {
  int i = blockIdx.x * 256 + threadIdx.x;
  if (i < BHN * NF) su[i] = 0.f;
  if (i < BHN * HD) vsum[i] = 0.f;
  if (i == 0) *stabEnc = 0u;
}

// k_sum[m] = ratio*(e^-stab*su[m] + eps*SEQ); ksum_tot = sum_m k_sum
__global__ __launch_bounds__(256) void k_asm_ksum(const float* __restrict__ su, const u32* __restrict__ stabEnc,
                                                  float* __restrict__ k_sum, float* __restrict__ ksum_tot) {
  __shared__ float red[256];
  int z = blockIdx.x, m = threadIdx.x;
  float es = __expf(-decf(*stabEnc));
  float v = ratf() * (es * su[(long)z * NF + m] + kepsf() * (float)SEQ);
  k_sum[(long)z * NF + m] = v;
  red[m] = v;
  __syncthreads();
  for (int s = 128; s > 0; s >>= 1) {
    if (m < s) red[m] += red[m + s];
    __syncthreads();
  }
  if (m == 0) ksum_tot[z] = red[0];
}

// ct[d][m] = ratio*(e^-stab*sum_ck part[m][d] + eps*vsum[d]) -> bf16; ctsum[d]
__global__ __launch_bounds__(256) void k_asm_ct(const u16* __restrict__ part, const float* __restrict__ vsum,
                                                const u32* __restrict__ stabEnc, u16* __restrict__ ct_bf,
                                                float* __restrict__ ctsum) {
  __shared__ float red[4][64];
  const int z = blockIdx.x, tid = threadIdx.x;
  const int w = tid >> 6, l = tid & 63;
  float es = __expf(-decf(*stabEnc));
  float vs = vsum[(long)z * HD + l];
  float csum = 0.f;
  for (int m = w; m < NF; m += 4) {
    float a = 0.f;
#pragma unroll
    for (int ck = 0; ck < 16; ck++)
      a += bf2f(part[((long)(z * 16 + ck) * NF + m) * HD + l]);
    float cv = ratf() * (es * a + kepsf() * vs);
    ct_bf[((long)z * HD + l) * NF + m] = f2bf(cv);
    csum += cv;
  }
  red[w][l] = csum;
  __syncthreads();
  if (tid < 64)
    ctsum[(long)z * HD + tid] = red[0][tid] + red[1][tid] + red[2][tid] + red[3][tid];
}

// ---------------------------------------------------------------------------
extern "C" void kernel_launch(void* const* d_in, const int* in_sizes, int n_in,
                              void* d_out, int out_size, void* d_ws, size_t ws_size,
                              hipStream_t stream) {
  const float* x    = (const float*)d_in[0];
  const float* Wq   = (const float*)d_in[1];
  const float* bq   = (const float*)d_in[2];
  const float* Wk   = (const float*)d_in[3];
  const float* bk   = (const float*)d_in[4];
  const float* Wv   = (const float*)d_in[5];
  const float* bv   = (const float*)d_in[6];
  const float* Wo   = (const float*)d_in[7];
  const float* bo   = (const float*)d_in[8];
  const float* proj = (const float*)d_in[9];

  char* base = (char*)d_ws;
  size_t off = 0;
  auto alloc = [&](size_t bytes) {
    off = (off + 255) & ~(size_t)255;
    char* r = base + off;
    off += bytes;
    return r;
  };
  // ~145 MB total: qkv fused, attn_bf aliased to xb.
  u16*  xb     = (u16*)alloc((size_t)TOKN * EMB * 2);   // 33.5 MB; -> part -> attn_bf
  u16*  wqkv   = (u16*)alloc((size_t)3 * EMB * EMB * 2);// 6 MB [Wq;Wk;Wv]
  u16*  wob    = (u16*)alloc((size_t)EMB * EMB * 2);
  u16*  projb  = (u16*)alloc((size_t)NF * HD * 2);
  u16*  qkv    = (u16*)alloc((size_t)TOKN * LDQ * 2);   // 100.7 MB fused output
  float* su    = (float*)alloc((size_t)BHN * NF * 4);
  float* k_sum = (float*)alloc((size_t)BHN * NF * 4);
  float* ksum_t= (float*)alloc((size_t)BHN * 4);
  float* vsum  = (float*)alloc((size_t)BHN * HD * 4);
  float* ctsum = (float*)alloc((size_t)BHN * HD * 4);
  u32*  stabE  = (u32*)alloc(256);
  u16*  ct_bf  = (u16*)alloc((size_t)BHN * HD * NF * 2); // 2 MB
  u16*  qb     = qkv;              // column slices, row stride LDQ
  u16*  kb     = qkv + EMB;
  u16*  vb     = qkv + 2 * EMB;
  u16*  part   = xb;               // xb dead after QKV GEMM
  u16*  attn_bf= xb;               // part dead after k_asm_ct (step 6)
  u16*  vT     = (u16*)d_out;      // d_out scratch until final GEMM

  // 0. init atomic accumulators
  k_init<<<64, 256, 0, stream>>>(su, vsum, stabE);
  // 1. fp32 -> bf16
  k_cvt<<<(TOKN * EMB / 4 + 255) / 256, 256, 0, stream>>>(x, xb, (long)TOKN * EMB / 4);
  k_cvt<<<(EMB * EMB / 4 + 255) / 256, 256, 0, stream>>>(Wq, wqkv, (long)EMB * EMB / 4);
  k_cvt<<<(EMB * EMB / 4 + 255) / 256, 256, 0, stream>>>(Wk, wqkv + (size_t)EMB * EMB, (long)EMB * EMB / 4);
  k_cvt<<<(EMB * EMB / 4 + 255) / 256, 256, 0, stream>>>(Wv, wqkv + (size_t)2 * EMB * EMB, (long)EMB * EMB / 4);
  k_cvt<<<(EMB * EMB / 4 + 255) / 256, 256, 0, stream>>>(Wo, wob, (long)EMB * EMB / 4);
  k_cvt<<<(NF * HD / 4 + 255) / 256, 256, 0, stream>>>(proj, projb, (long)NF * HD / 4);
  // 2. fused QKV projection: [16384][3072] = xb * [Wq;Wk;Wv]^T + bias
  k_gemm3<<<dim3(LDQ / 128, TOKN / 128), 256, 0, stream>>>(xb, wqkv, qkv, bq, bk, bv,
                                                           EMB, EMB, EMB, LDQ);
  // 3. v transpose into d_out scratch + vsum
  k_vT<<<dim3(SEQ / 64, BHN), 256, 0, stream>>>(vb, vT, vsum);
  // 4. fused key features + context partials (writes part=xb after xb dead)
  k_fk_ctx<<<dim3(16, BHN), 256, 0, stream>>>(kb, vT, projb, part, su, stabE);
  // 5. assemble k_sum / ksum_tot
  k_asm_ksum<<<BHN, 256, 0, stream>>>(su, stabE, k_sum, ksum_t);
  // 6. assemble context (bf16) + ctsum
  k_asm_ct<<<BHN, 256, 0, stream>>>(part, vsum, stabE, ct_bf, ctsum);
  // 7. fused query features + attention (writes attn_bf=xb after part dead)
  k_fq_attn<<<dim3(SEQ / 64, BHN), 256, 0, stream>>>(qb, projb, k_sum, ksum_t, ct_bf, ctsum, attn_bf);
  // 8. output projection (fp32 out, overwrites vT scratch region)
  k_gemm<false><<<dim3(EMB / 128, TOKN / 128), 256, 0, stream>>>(attn_bf, wob, d_out, bo, EMB, EMB, EMB, EMB);
}

// Round 14
// 472.615 us; speedup vs baseline: 1.6997x; 1.0620x over previous
//
#include <hip/hip_runtime.h>
#include <hip/hip_bf16.h>
#include <stdint.h>

// Performer (FAVOR+) forward, MI355X/gfx950.
// B=4, N=4096, E=1024, H=16, D=64, M(features)=256.
// bf16 MFMA (16x16x32) everywhere matmul-shaped, fp32 accumulate/epilogues.
// kf never materialized: kf = ratio*(e^-stab * U + eps), U = exp(dd-diag) is
// stab-free; context/k_sum assembled linearly from fused U^T·v and U^T·1.
// R5: fk_ctx accR strip (85.5->74us). R6: fq_attn spill fix (578->563us).
// R7/R8/R9 FAILED (spill). R10 revert = 560.7us; fk_ctx CLOSED at 74us.
// R11: QKV fused into k_gemm3 (554.2us). R12: BK=64 + both-sides XOR swizzle
// (513.0us; conflicts 12.6M->0). R13: counted-vmcnt double-buffer pipeline
// (501.9us; k_gemm3 129.5us/795TF = m97-structure ceiling; MfmaUtil 34%,
// VALU 26%, no spill). K-loop FROZEN (256^2 needs full 8-phase; measured
// tables say 2-phase 256^2 regresses).
// R14: traffic/launch harvest. (a) k_vT deleted: gemm3 v-segment epilogue
// writes transposed vT scatter (u16x4 runs contiguous along n) + vsum
// atomics directly, and SKIPS the dead qkv v-write (nothing else read it)
// -> net -67MB traffic; qkv stride 3072->2048. (b) 6x k_cvt + k_init fused
// into one segmented k_cvt_all (compile-time bounds) -> -6 launches.

#define TOKN  16384
#define SEQ   4096
#define EMB   1024
#define LDQ   2048   // fused qk row stride (v never materialized in qkv)
#define NHEAD 16
#define HD    64
#define NF    256
#define BHN   64   // batch*heads

static __device__ __forceinline__ constexpr float c1f()  { return 0.35355339059327379f; } // 64^-0.25
static __device__ __forceinline__ constexpr float ratf() { return 0.0625f; }              // 256^-0.5
static __device__ __forceinline__ constexpr float kepsf(){ return 1e-4f; }

typedef unsigned short u16;
typedef unsigned int   u32;
typedef __attribute__((ext_vector_type(8))) short bf16x8;
typedef __attribute__((ext_vector_type(4))) float f32x4;
typedef __attribute__((ext_vector_type(4))) u16   u16x4;

union U8 { bf16x8 v8; u16x4 q[2]; };

__device__ __forceinline__ float bf2f(u16 u) { return __uint_as_float(((u32)u) << 16); }
__device__ __forceinline__ u16 f2bf(float f) {
  u32 u = __float_as_uint(f);
  u += 0x7fffu + ((u >> 16) & 1u);   // RNE
  return (u16)(u >> 16);
}
// order-preserving float<->uint encoding for atomicMax on a float
__device__ __forceinline__ u32 encf(float f) {
  u32 u = __float_as_uint(f);
  return (u & 0x80000000u) ? ~u : (u | 0x80000000u);
}
__device__ __forceinline__ float decf(u32 e) {
  u32 u = (e & 0x80000000u) ? (e & 0x7fffffffu) : ~e;
  return __uint_as_float(u);
}

__device__ __forceinline__ void gl2lds16(const u16* g, void* l) {
  __builtin_amdgcn_global_load_lds(
      (const __attribute__((address_space(1))) u32*)g,
      (__attribute__((address_space(3))) u32*)l, 16, 0, 0);
}

#define ZERO_ACC(acc)                         \
  _Pragma("unroll") for (int _i = 0; _i < 4; _i++) \
  _Pragma("unroll") for (int _j = 0; _j < 4; _j++) acc[_i][_j] = (f32x4)0.0f;

// ---------------------------------------------------------------------------
// MFMA GEMM core, R13 (frozen): BK=64, double-buffered LDS, counted-vmcnt
// pipeline. C[m][n] += sum_k A[m][k]*B[n][k] (row-major, K contiguous).
// 256 thr = 4 waves; wave tile 64x64 (4x4 of 16x16x32).
// Staging pre-permutes the global source granule (part ^ (row&7)) so the
// linear global_load_lds dest equals the swizzled layout; ds_read XORs the
// same involution -> conflict-free b128 reads (verified: conflicts 0, R12).
// Pipeline: stage(t+1) -> vmcnt(8) [tile t landed, t+1 in flight] ->
// s_barrier -> compute(buf t) -> s_barrier.
// ---------------------------------------------------------------------------
template <int BM, int BN>
__device__ __forceinline__ void gemm_core(const u16* __restrict__ Ag, long lda,
                                          const u16* __restrict__ Bg, long ldb,
                                          int K, u16* sA, u16* sB,
                                          f32x4 (&acc)[4][4]) {
  const int tid = threadIdx.x;
  const int w = tid >> 6, l = tid & 63;
  constexpr int WM = BM / 64;
  const int wm = w % WM, wn = w / WM;
  const int lrow = l & 15, g4 = l >> 4;    // g4 = 16B-granule index in K-half
  constexpr int AI = (BM * 8) / 256;       // 16B chunks per tile / 256 thr
  constexpr int BI = (BN * 8) / 256;
  static_assert(AI + BI == 8, "vmcnt(8) literal assumes 8 loads/thread/tile");
  constexpr int ABUF = BM * 64;            // u16 elems per buffer
  constexpr int BBUF = BN * 64;

  auto stage = [&](int k0, int sel) {
#pragma unroll
    for (int i = 0; i < AI; i++) {
      int q = i * 256 + tid;
      int row = q >> 3, part = (q & 7) ^ (row & 7);   // inverse-swz source
      gl2lds16(Ag + (long)row * lda + k0 + part * 8,
               (char*)(sA + sel * ABUF) + i * 4096 + w * 1024);
    }
#pragma unroll
    for (int i = 0; i < BI; i++) {
      int q = i * 256 + tid;
      int row = q >> 3, part = (q & 7) ^ (row & 7);
      gl2lds16(Bg + (long)row * ldb + k0 + part * 8,
               (char*)(sB + sel * BBUF) + i * 4096 + w * 1024);
    }
  };

  stage(0, 0);
  const int NT = K >> 6;
  for (int t = 0; t < NT; ++t) {
    const int sel = t & 1;
    if (t + 1 < NT) {
      stage((t + 1) * 64, sel ^ 1);
      asm volatile("s_waitcnt vmcnt(8)" ::: "memory");   // tile t landed; t+1 in flight
    } else {
      asm volatile("s_waitcnt vmcnt(0)" ::: "memory");   // epilogue drain
    }
    __builtin_amdgcn_s_barrier();
    __builtin_amdgcn_sched_barrier(0);
    const u16* pA = sA + sel * ABUF;
    const u16* pB = sB + sel * BBUF;
#pragma unroll
    for (int kk = 0; kk < 2; kk++) {
      bf16x8 af[4], bfr[4];
#pragma unroll
      for (int mt = 0; mt < 4; mt++) {
        int row = wm * 64 + mt * 16 + lrow;
        af[mt] = *(const bf16x8*)(pA + row * 64 + (((kk * 4 + g4) ^ (row & 7)) * 8));
      }
#pragma unroll
      for (int nt = 0; nt < 4; nt++) {
        int row = wn * 64 + nt * 16 + lrow;
        bfr[nt] = *(const bf16x8*)(pB + row * 64 + (((kk * 4 + g4) ^ (row & 7)) * 8));
      }
#pragma unroll
      for (int mt = 0; mt < 4; mt++)
#pragma unroll
        for (int nt = 0; nt < 4; nt++)
          acc[mt][nt] = __builtin_amdgcn_mfma_f32_16x16x32_bf16(af[mt], bfr[nt], acc[mt][nt], 0, 0, 0);
    }
    __builtin_amdgcn_s_barrier();   // readers done before tile t+2 overwrites this buffer
  }
}

// ---------------------------------------------------------------------------
// Big 128x128 GEMM: C = A*B^T + bias. XCD-aware block swizzle.
// ---------------------------------------------------------------------------
template <bool BF16OUT>
__global__ __launch_bounds__(256) void k_gemm(const u16* __restrict__ A, const u16* __restrict__ Bw,
                                              void* __restrict__ Cout, const float* __restrict__ bias,
                                              int K, int lda, int ldb, int ldc) {
  __shared__ __align__(16) u16 sA[2 * 128 * 64];
  __shared__ __align__(16) u16 sB[2 * 128 * 64];
  const int nbx = gridDim.x;
  const int nwg = nbx * gridDim.y;
  int lin = blockIdx.y * nbx + blockIdx.x;
  if ((nwg & 7) == 0) {                    // bijective XCD swizzle (nwg%8==0)
    int per = nwg >> 3;
    lin = (lin & 7) * per + (lin >> 3);
  }
  const int m0 = (lin / nbx) * 128, n0 = (lin % nbx) * 128;
  f32x4 acc[4][4]; ZERO_ACC(acc);
  gemm_core<128, 128>(A + (long)m0 * lda, lda, Bw + (long)n0 * ldb, ldb, K, sA, sB, acc);
  const int l = threadIdx.x & 63, w = threadIdx.x >> 6;
  const int wm = w & 1, wn = w >> 1, lr4 = (l >> 4) * 4, lc = l & 15;
#pragma unroll
  for (int nt = 0; nt < 4; nt++) {
    int gcol = n0 + wn * 64 + nt * 16 + lc;
    float bia = bias[gcol];
#pragma unroll
    for (int mt = 0; mt < 4; mt++)
#pragma unroll
      for (int r = 0; r < 4; r++) {
        int grow = m0 + wm * 64 + mt * 16 + lr4 + r;
        float v = acc[mt][nt][r] + bia;
        if (BF16OUT) ((u16*)Cout)[(long)grow * ldc + gcol] = f2bf(v);
        else         ((float*)Cout)[(long)grow * ldc + gcol] = v;
      }
  }
}

// ---------------------------------------------------------------------------
// Fused QKV GEMM (N=3072 compute). Weight rows 0..1023=Wq, 1024..2047=Wk,
// 2048..3071=Wv. Blocks never straddle a 1024-col boundary (1024%128==0).
// R14: seg 0/1 (q,k) write qkv (stride LDQ=2048); seg 2 (v) writes the
// TRANSPOSED vT[bh][d][n] scatter (u16x4 contiguous along n) + vsum atomics
// instead (the qkv v-slice was dead — only k_vT consumed it).
// ---------------------------------------------------------------------------
__global__ __launch_bounds__(256) void k_gemm3(const u16* __restrict__ A, const u16* __restrict__ Bw,
                                               u16* __restrict__ Cout,
                                               const float* __restrict__ b0, const float* __restrict__ b1,
                                               const float* __restrict__ b2,
                                               u16* __restrict__ vTout, float* __restrict__ vsum,
                                               int K, int lda, int ldb, int ldc) {
  __shared__ __align__(16) u16 sA[2 * 128 * 64];
  __shared__ __align__(16) u16 sB[2 * 128 * 64];
  const int nbx = gridDim.x;
  const int nwg = nbx * gridDim.y;
  int lin = blockIdx.y * nbx + blockIdx.x;
  if ((nwg & 7) == 0) {                    // bijective XCD swizzle (nwg%8==0)
    int per = nwg >> 3;
    lin = (lin & 7) * per + (lin >> 3);
  }
  const int m0 = (lin / nbx) * 128, n0 = (lin % nbx) * 128;
  f32x4 acc[4][4]; ZERO_ACC(acc);
  gemm_core<128, 128>(A + (long)m0 * lda, lda, Bw + (long)n0 * ldb, ldb, K, sA, sB, acc);
  const int l = threadIdx.x & 63, w = threadIdx.x >> 6;
  const int wm = w & 1, wn = w >> 1, lr4 = (l >> 4) * 4, lc = l & 15;
  const int seg = n0 >> 10;
  if (seg < 2) {
    const float* bias = seg == 0 ? b0 : b1;
#pragma unroll
    for (int nt = 0; nt < 4; nt++) {
      int gcol = n0 + wn * 64 + nt * 16 + lc;
      float bia = bias[gcol & 1023];
#pragma unroll
      for (int mt = 0; mt < 4; mt++)
#pragma unroll
        for (int r = 0; r < 4; r++) {
          int grow = m0 + wm * 64 + mt * 16 + lr4 + r;
          Cout[(long)grow * ldc + gcol] = f2bf(acc[mt][nt][r] + bia);
        }
    }
  } else {
    // v segment: transposed write vT[((b*16+h)*64+d)][n], n = token & 4095.
    // m0 is 128-aligned -> whole block shares one batch b; 4-run along r is
    // contiguous in n and never crosses a batch boundary.
    const int b = m0 >> 12;
#pragma unroll
    for (int nt = 0; nt < 4; nt++) {
      int e = (n0 & 1023) + wn * 64 + nt * 16 + lc;   // 0..1023 within v
      int hh = e >> 6, d = e & 63;
      float bia = b2[e];
      long vbase = ((long)((b * 16 + hh) * 64 + d)) * SEQ;
      float s = 0.f;
#pragma unroll
      for (int mt = 0; mt < 4; mt++) {
        int grow0 = m0 + wm * 64 + mt * 16 + lr4;
        u16x4 pk;
#pragma unroll
        for (int r = 0; r < 4; r++) {
          float v = acc[mt][nt][r] + bia;
          pk[r] = f2bf(v);
          s += v;
        }
        *(u16x4*)&vTout[vbase + (grow0 & 4095)] = pk;
      }
      // reduce over lanes sharing this column (l ^ 16, l ^ 32 have same lc)
      s += __shfl_xor(s, 16);
      s += __shfl_xor(s, 32);
      if (l < 16) atomicAdd(&vsum[(b * 16 + hh) * 64 + d], s);
    }
  }
}

// ---------------------------------------------------------------------------
// Fused key features + context partials, BARRIER-FREE. (CLOSED at 74 us.)
// kb is the k slice of qkv (row stride LDQ).
// ---------------------------------------------------------------------------
__global__ __launch_bounds__(256, 2) void k_fk_ctx(const u16* __restrict__ kb, const u16* __restrict__ vT,
                                                   const u16* __restrict__ projb, u16* __restrict__ part,
                                                   float* __restrict__ su, u32* __restrict__ stabEnc) {
  __shared__ __align__(16) u16 sU[4][64 * 64];   // per-wave 8KB regions
  const int ck = blockIdx.x, bh = blockIdx.y, b = bh >> 4, h = bh & 15;
  const int tid = threadIdx.x, w = tid >> 6, l = tid & 63;
  const int c = l & 15, g = l >> 4;
  u16* sUw = &sU[w][0];
  const int sw = c & 7;

  // proj B-fragments in registers: features w*64+nt*16+c, k = k0*32+g*8+j
  bf16x8 pf[4][2];
#pragma unroll
  for (int nt = 0; nt < 4; nt++)
#pragma unroll
    for (int k0 = 0; k0 < 2; k0++)
      pf[nt][k0] = *(const bf16x8*)&projb[(w * 64 + nt * 16 + c) * 64 + k0 * 32 + g * 8];

  f32x4 acc2[4][4]; ZERO_ACC(acc2);   // ctx: rows=features(wave-local), cols=d
  float suv[4] = {0.f, 0.f, 0.f, 0.f};
  float amax = -1e30f;                // max raw acc; stab = c1*amax (monotone)
  const long tok0 = (long)b * SEQ + ck * 256;

  for (int s = 0; s < 4; s++) {
    const long t0 = tok0 + s * 64;
    // A-fragments direct from global: token = mt*16+c, k(d) = k0*32+g*8+j
    bf16x8 af[4][2];
#pragma unroll
    for (int mt = 0; mt < 4; mt++)
#pragma unroll
      for (int k0 = 0; k0 < 2; k0++)
        af[mt][k0] = *(const bf16x8*)&kb[(t0 + mt * 16 + c) * LDQ + h * HD + k0 * 32 + g * 8];
    // hoist vT B-frags for the ctx GEMM: HBM/L3 latency hides under the
    // feature GEMM + epilogue below.
    bf16x8 vf[2][4];
#pragma unroll
    for (int k0 = 0; k0 < 2; k0++)
#pragma unroll
      for (int nt = 0; nt < 4; nt++)
        vf[k0][nt] = *(const bf16x8*)&vT[((long)bh * HD + nt * 16 + c) * SEQ +
                                         ck * 256 + s * 64 + k0 * 32 + g * 8];

    // per-token-granule mt: diag + one 16-row strip of the feature GEMM +
    // epilogue, with accR recycled (peak acc pressure 64+16 not 64+64).
#pragma unroll
    for (int mt = 0; mt < 4; mt++) {
      float ss = 0.f;
#pragma unroll
      for (int k0 = 0; k0 < 2; k0++)
#pragma unroll
        for (int j = 0; j < 8; j++) {
          float v = bf2f((u16)af[mt][k0][j]);
          ss += v * v;
        }
      ss += __shfl_xor(ss, 16);
      ss += __shfl_xor(ss, 32);
      const float dgrow = ss * 0.0625f;   // diag of token mt*16+c
      f32x4 accR[4];
#pragma unroll
      for (int nt = 0; nt < 4; nt++) accR[nt] = (f32x4)0.0f;
#pragma unroll
      for (int k0 = 0; k0 < 2; k0++)
#pragma unroll
        for (int nt = 0; nt < 4; nt++)
          accR[nt] = __builtin_amdgcn_mfma_f32_16x16x32_bf16(af[mt][k0], pf[nt][k0], accR[nt], 0, 0, 0);
      // epilogue: U = exp(c1*acc - diag) -> per-wave sU (swizzled), su, stab
      float dg[4];
#pragma unroll
      for (int r = 0; r < 4; r++) dg[r] = __shfl(dgrow, g * 4 + r);
#pragma unroll
      for (int nt = 0; nt < 4; nt++) {
        u16x4 pk;
#pragma unroll
        for (int r = 0; r < 4; r++) {
          float a = accR[nt][r];
          amax = fmaxf(amax, a);
          float U = __expf(fmaf(a, c1f(), -dg[r]));
          pk[r] = f2bf(U);
          suv[nt] += U;
        }
        // write tokens granule G=mt*4+g (pair P=mt*2+(g>>1), b=g&1), row nt*16+c
        *(u16x4*)&sUw[(nt * 16 + c) * 64 + (((mt * 2 + (g >> 1)) ^ sw) * 2 + (g & 1)) * 4] = pk;
      }
    }
    // ctx GEMM: acc2[m][d] += sum_n U^T[m][n] * vT[d][n]  (intra-wave sU reads)
#pragma unroll
    for (int k0 = 0; k0 < 2; k0++) {
      bf16x8 uf[4];
#pragma unroll
      for (int mt = 0; mt < 4; mt++)
        uf[mt] = *(const bf16x8*)&sUw[(mt * 16 + c) * 64 + ((k0 * 4 + g) ^ sw) * 8];
#pragma unroll
      for (int mt = 0; mt < 4; mt++)
#pragma unroll
        for (int nt = 0; nt < 4; nt++)
          acc2[mt][nt] = __builtin_amdgcn_mfma_f32_16x16x32_bf16(uf[mt], vf[k0][nt], acc2[mt][nt], 0, 0, 0);
    }
  }
  // store ctx partials bf16: part[z][m][d]
  const long zp = (long)(bh * 16 + ck);
#pragma unroll
  for (int mt = 0; mt < 4; mt++)
#pragma unroll
    for (int nt = 0; nt < 4; nt++)
#pragma unroll
      for (int r = 0; r < 4; r++) {
        int m = w * 64 + mt * 16 + g * 4 + r;
        int d = nt * 16 + c;
        part[(zp * NF + m) * HD + d] = f2bf(acc2[mt][nt][r]);
      }
  // su atomic (reduce over lane groups sharing c)
#pragma unroll
  for (int nt = 0; nt < 4; nt++) {
    float v = suv[nt];
    v += __shfl_xor(v, 16);
    v += __shfl_xor(v, 32);
    if (l < 16) atomicAdd(&su[bh * NF + w * 64 + nt * 16 + l], v);
  }
  for (int o = 32; o; o >>= 1) amax = fmaxf(amax, __shfl_xor(amax, o));
  if (l == 0) atomicMax(stabEnc, encf(c1f() * amax));
}

// ---------------------------------------------------------------------------
// Fused query features + attention. One block per (64-token tile, bh).
// qb is the q slice of qkv (row stride LDQ); attn_bf separate (stride EMB).
// ---------------------------------------------------------------------------
__global__ __launch_bounds__(256, 4) void k_fq_attn(const u16* __restrict__ qb, const u16* __restrict__ projb,
                                                    const float* __restrict__ k_sum, const float* __restrict__ ksum_tot,
                                                    const u16* __restrict__ ct_bf, const float* __restrict__ ctsum,
                                                    u16* __restrict__ attn_bf) {
  __shared__ __align__(16) u16 sUq[64 * 256];    // Uq [token][m], 16B-granule swizzled
  __shared__ float redmax[4][64];
  __shared__ float redsum[4][64];
  const int bh = blockIdx.y, b = bh >> 4, h = bh & 15;
  const long t0 = (long)b * SEQ + blockIdx.x * 64;
  const int tid = threadIdx.x, w = tid >> 6, l = tid & 63;
  const int lrow = l & 15, lk = (l >> 4) * 8, lr4 = (l >> 4) * 4, lc = l & 15;

  // A-frags: proj rows = features w*64+mt*16+lrow, k = k0*32+lk+j
  bf16x8 pf[4][2];
#pragma unroll
  for (int mt = 0; mt < 4; mt++)
#pragma unroll
    for (int k0 = 0; k0 < 2; k0++)
      pf[mt][k0] = *(const bf16x8*)&projb[(w * 64 + mt * 16 + lrow) * 64 + k0 * 32 + lk];
  // B-frags: q rows = tokens nt*16+lrow (direct from global, fk_ctx pattern).
  bf16x8 af[4][2];
#pragma unroll
  for (int nt = 0; nt < 4; nt++)
#pragma unroll
    for (int k0 = 0; k0 < 2; k0++)
      af[nt][k0] = *(const bf16x8*)&qb[(t0 + nt * 16 + lrow) * LDQ + h * HD + k0 * 32 + lk];

  // inline diag per token: each lane ends with diag of its OWN token nt*16+lc
  float dgq[4];
#pragma unroll
  for (int nt = 0; nt < 4; nt++) {
    float ss = 0.f;
#pragma unroll
    for (int k0 = 0; k0 < 2; k0++)
#pragma unroll
      for (int j = 0; j < 8; j++) {
        float v = bf2f((u16)af[nt][k0][j]);
        ss += v * v;
      }
    ss += __shfl_xor(ss, 16);
    ss += __shfl_xor(ss, 32);
    dgq[nt] = ss * 0.0625f;
  }

  // k_sum for this lane's 16 features (mt, lr4+r)
  f32x4 ksr[4];
#pragma unroll
  for (int mt = 0; mt < 4; mt++)
    ksr[mt] = *(const f32x4*)&k_sum[(long)bh * NF + w * 64 + mt * 16 + lr4];

  // per-token-granule nt: 16-col strip of the feature GEMM (accC recycled)
  // + epilogue: U -> sUq (u16x4 along features, swizzled), per-token max,
  // sum(U*ksum) partials.
#pragma unroll
  for (int nt = 0; nt < 4; nt++) {
    f32x4 accC[4];
#pragma unroll
    for (int mt = 0; mt < 4; mt++) accC[mt] = (f32x4)0.0f;
#pragma unroll
    for (int k0 = 0; k0 < 2; k0++)
#pragma unroll
      for (int mt = 0; mt < 4; mt++)
        accC[mt] = __builtin_amdgcn_mfma_f32_16x16x32_bf16(pf[mt][k0], af[nt][k0], accC[mt], 0, 0, 0);

    const int tok = nt * 16 + lc;
    const int trow = tok * NF, tsw = tok & 7;
    float vmax = -1e30f, s = 0.f;
#pragma unroll
    for (int mt = 0; mt < 4; mt++) {
      const int fb = w * 64 + mt * 16 + lr4;   // multiple of 4
      u16x4 pk;
#pragma unroll
      for (int r = 0; r < 4; r++) {
        float dd = c1f() * accC[mt][r];
        vmax = fmaxf(vmax, dd);
        float U = __expf(dd - dgq[nt]);
        pk[r] = f2bf(U);
        s += U * ksr[mt][r];
      }
      *(u16x4*)&sUq[trow + (((fb >> 3) ^ tsw) << 3) + (fb & 7)] = pk;
    }
    vmax = fmaxf(vmax, __shfl_xor(vmax, 16));
    vmax = fmaxf(vmax, __shfl_xor(vmax, 32));
    s += __shfl_xor(s, 16);
    s += __shfl_xor(s, 32);
    if (l < 16) { redmax[w][nt * 16 + l] = vmax; redsum[w][nt * 16 + l] = s; }
  }
  __syncthreads();
  // attention GEMM: wave w owns d in [w*16, w*16+16); K = 256 features
  f32x4 acc2[4];
#pragma unroll
  for (int mt = 0; mt < 4; mt++) acc2[mt] = (f32x4)0.0f;
#pragma unroll
  for (int kk = 0; kk < 8; kk++) {
    bf16x8 bfr = *(const bf16x8*)&ct_bf[((long)bh * HD + w * 16 + lrow) * NF + kk * 32 + lk];
#pragma unroll
    for (int mt = 0; mt < 4; mt++) {
      int row = mt * 16 + lrow;
      bf16x8 a2 = *(const bf16x8*)&sUq[row * NF + (((kk * 4 + (l >> 4)) ^ (row & 7)) * 8)];
      acc2[mt] = __builtin_amdgcn_mfma_f32_16x16x32_bf16(a2, bfr, acc2[mt], 0, 0, 0);
    }
  }
  // epilogue: alpha/beta per row, write bf16 attn in [B,N,E]
  const float kst = ksum_tot[bh];
  const float cts = ctsum[(long)bh * HD + w * 16 + lc];
#pragma unroll
  for (int mt = 0; mt < 4; mt++)
#pragma unroll
    for (int r = 0; r < 4; r++) {
      int row = mt * 16 + lr4 + r;
      float rs = fmaxf(fmaxf(redmax[0][row], redmax[1][row]),
                       fmaxf(redmax[2][row], redmax[3][row]));
      float S1 = redsum[0][row] + redsum[1][row] + redsum[2][row] + redsum[3][row];
      float ers = __expf(-rs);
      float di = 1.0f / (ratf() * (ers * S1 + kepsf() * kst));
      float a_ = di * ratf() * ers;
      float b_ = di * ratf() * kepsf();
      float ov = a_ * acc2[mt][r] + b_ * cts;
      attn_bf[(t0 + row) * EMB + h * HD + w * 16 + lc] = f2bf(ov);
    }
}

// --------------------------- glue kernels ----------------------------------
// R14: single segmented convert+init kernel (all bounds compile-time).
#define NF4_X (TOKN * EMB / 4)
#define NF4_W (EMB * EMB / 4)
#define NF4_P (NF * HD / 4)
__global__ void k_cvt_all(const float* __restrict__ x,
                          const float* __restrict__ Wq, const float* __restrict__ Wk,
                          const float* __restrict__ Wv, const float* __restrict__ Wo,
                          const float* __restrict__ proj,
                          u16* __restrict__ xb, u16* __restrict__ wqkv,
                          u16* __restrict__ wob, u16* __restrict__ projb,
                          float* __restrict__ su, float* __restrict__ vsum,
                          u32* __restrict__ stabEnc) {
  const long b0 = NF4_X;
  const long b1 = b0 + NF4_W, b2 = b1 + NF4_W, b3 = b2 + NF4_W, b4 = b3 + NF4_W;
  const long b5 = b4 + NF4_P;
  long i = (long)blockIdx.x * 256 + threadIdx.x;
  const float* s; u16* d; long off;
  if      (i < b0) { s = x;    d = xb;                          off = i; }
  else if (i < b1) { s = Wq;   d = wqkv;                        off = i - b0; }
  else if (i < b2) { s = Wk;   d = wqkv + (size_t)EMB * EMB;    off = i - b1; }
  else if (i < b3) { s = Wv;   d = wqkv + (size_t)2 * EMB * EMB; off = i - b2; }
  else if (i < b4) { s = Wo;   d = wob;                         off = i - b3; }
  else if (i < b5) { s = proj; d = projb;                       off = i - b4; }
  else {
    long j = i - b5;
    if (j < BHN * NF) su[j] = 0.f;
    else if (j < BHN * NF + BHN * HD) vsum[j - BHN * NF] = 0.f;
    else if (j == BHN * NF + BHN * HD) *stabEnc = 0u;
    return;
  }
  float4 v = ((const float4*)s)[off];
  u16x4 o = { f2bf(v.x), f2bf(v.y), f2bf(v.z), f2bf(v.w) };
  ((u16x4*)d)[off] = o;
}

// k_sum[m] = ratio*(e^-stab*su[m] + eps*SEQ); ksum_tot = sum_m k_sum
__global__ __launch_bounds__(256) void k_asm_ksum(const float* __restrict__ su, const u32* __restrict__ stabEnc,
                                                  float* __restrict__ k_sum, float* __restrict__ ksum_tot) {
  __shared__ float red[256];
  int z = blockIdx.x, m = threadIdx.x;
  float es = __expf(-decf(*stabEnc));
  float v = ratf() * (es * su[(long)z * NF + m] + kepsf() * (float)SEQ);
  k_sum[(long)z * NF + m] = v;
  red[m] = v;
  __syncthreads();
  for (int s = 128; s > 0; s >>= 1) {
    if (m < s) red[m] += red[m + s];
    __syncthreads();
  }
  if (m == 0) ksum_tot[z] = red[0];
}

// ct[d][m] = ratio*(e^-stab*sum_ck part[m][d] + eps*vsum[d]) -> bf16; ctsum[d]
__global__ __launch_bounds__(256) void k_asm_ct(const u16* __restrict__ part, const float* __restrict__ vsum,
                                                const u32* __restrict__ stabEnc, u16* __restrict__ ct_bf,
                                                float* __restrict__ ctsum) {
  __shared__ float red[4][64];
  const int z = blockIdx.x, tid = threadIdx.x;
  const int w = tid >> 6, l = tid & 63;
  float es = __expf(-decf(*stabEnc));
  float vs = vsum[(long)z * HD + l];
  float csum = 0.f;
  for (int m = w; m < NF; m += 4) {
    float a = 0.f;
#pragma unroll
    for (int ck = 0; ck < 16; ck++)
      a += bf2f(part[((long)(z * 16 + ck) * NF + m) * HD + l]);
    float cv = ratf() * (es * a + kepsf() * vs);
    ct_bf[((long)z * HD + l) * NF + m] = f2bf(cv);
    csum += cv;
  }
  red[w][l] = csum;
  __syncthreads();
  if (tid < 64)
    ctsum[(long)z * HD + tid] = red[0][tid] + red[1][tid] + red[2][tid] + red[3][tid];
}

// ---------------------------------------------------------------------------
extern "C" void kernel_launch(void* const* d_in, const int* in_sizes, int n_in,
                              void* d_out, int out_size, void* d_ws, size_t ws_size,
                              hipStream_t stream) {
  const float* x    = (const float*)d_in[0];
  const float* Wq   = (const float*)d_in[1];
  const float* bq   = (const float*)d_in[2];
  const float* Wk   = (const float*)d_in[3];
  const float* bk   = (const float*)d_in[4];
  const float* Wv   = (const float*)d_in[5];
  const float* bv   = (const float*)d_in[6];
  const float* Wo   = (const float*)d_in[7];
  const float* bo   = (const float*)d_in[8];
  const float* proj = (const float*)d_in[9];

  char* base = (char*)d_ws;
  size_t off = 0;
  auto alloc = [&](size_t bytes) {
    off = (off + 255) & ~(size_t)255;
    char* r = base + off;
    off += bytes;
    return r;
  };
  // ~112 MB total: qkv stride 2048 (v transposed straight into d_out scratch).
  u16*  xb     = (u16*)alloc((size_t)TOKN * EMB * 2);   // 33.5 MB; -> part -> attn_bf
  u16*  wqkv   = (u16*)alloc((size_t)3 * EMB * EMB * 2);// 6 MB [Wq;Wk;Wv]
  u16*  wob    = (u16*)alloc((size_t)EMB * EMB * 2);
  u16*  projb  = (u16*)alloc((size_t)NF * HD * 2);
  u16*  qkv    = (u16*)alloc((size_t)TOKN * LDQ * 2);   // 67 MB (q|k only)
  float* su    = (float*)alloc((size_t)BHN * NF * 4);
  float* k_sum = (float*)alloc((size_t)BHN * NF * 4);
  float* ksum_t= (float*)alloc((size_t)BHN * 4);
  float* vsum  = (float*)alloc((size_t)BHN * HD * 4);
  float* ctsum = (float*)alloc((size_t)BHN * HD * 4);
  u32*  stabE  = (u32*)alloc(256);
  u16*  ct_bf  = (u16*)alloc((size_t)BHN * HD * NF * 2); // 2 MB
  u16*  qb     = qkv;              // column slices, row stride LDQ=2048
  u16*  kb     = qkv + 1024;
  u16*  part   = xb;               // xb dead after QKV GEMM
  u16*  attn_bf= xb;               // part dead after k_asm_ct (step 6)
  u16*  vT     = (u16*)d_out;      // d_out scratch until final GEMM

  // 1. fp32 -> bf16 conversions + accumulator init (one launch)
  {
    const long total = (long)NF4_X + 4 * NF4_W + NF4_P + BHN * NF + BHN * HD + 1;
    k_cvt_all<<<(unsigned)((total + 255) / 256), 256, 0, stream>>>(
        x, Wq, Wk, Wv, Wo, proj, xb, wqkv, wob, projb, su, vsum, stabE);
  }
  // 2. fused QKV projection: q,k -> qkv[16384][2048]; v -> vT (transposed) + vsum
  k_gemm3<<<dim3(3072 / 128, TOKN / 128), 256, 0, stream>>>(xb, wqkv, qkv, bq, bk, bv,
                                                            vT, vsum, EMB, EMB, EMB, LDQ);
  // 3. fused key features + context partials (writes part=xb after xb dead)
  k_fk_ctx<<<dim3(16, BHN), 256, 0, stream>>>(kb, vT, projb, part, su, stabE);
  // 4. assemble k_sum / ksum_tot
  k_asm_ksum<<<BHN, 256, 0, stream>>>(su, stabE, k_sum, ksum_t);
  // 5. assemble context (bf16) + ctsum
  k_asm_ct<<<BHN, 256, 0, stream>>>(part, vsum, stabE, ct_bf, ctsum);
  // 6. fused query features + attention (writes attn_bf=xb after part dead)
  k_fq_attn<<<dim3(SEQ / 64, BHN), 256, 0, stream>>>(qb, projb, k_sum, ksum_t, ct_bf, ctsum, attn_bf);
  // 7. output projection (fp32 out, overwrites vT scratch region)
  k_gemm<false><<<dim3(EMB / 128, TOKN / 128), 256, 0, stream>>>(attn_bf, wob, d_out, bo, EMB, EMB, EMB, EMB);
}